// Round 10
// baseline (240.730 us; speedup 1.0000x reference)
//
#include <hip/hip_runtime.h>
#include <hip/hip_bf16.h>

#define SEQ  2048
#define BSZ  2
#define DIM  256
#define NG   2
#define NQH  8
#define SUBQ 4
#define ROWS (SEQ*BSZ)   // 4096
#define NQKV 3072        // fused K|V|Q projection width
#define QROW 6144        // (BSZ*NQKV) elems per s step in QKV

typedef unsigned int uint32;
typedef unsigned short ushort;
typedef __attribute__((ext_vector_type(8))) short short8;
typedef __attribute__((ext_vector_type(4))) float f32x4;

__device__ __forceinline__ float bflo(uint32 u){
  union { uint32 i; float f; } c; c.i = u << 16; return c.f;
}
__device__ __forceinline__ float bfhi(uint32 u){
  union { uint32 i; float f; } c; c.i = u & 0xffff0000u; return c.f;
}
__device__ __forceinline__ uint32 pack2(float a, float b){
  __hip_bfloat16 ha = __float2bfloat16(a);
  __hip_bfloat16 hb = __float2bfloat16(b);
  unsigned short ua, ub;
  __builtin_memcpy(&ua, &ha, 2);
  __builtin_memcpy(&ub, &hb, 2);
  return (uint32)ua | ((uint32)ub << 16);
}
__device__ __forceinline__ ushort bf16bits(float v){
  __hip_bfloat16 h = __float2bfloat16(v);
  ushort u; __builtin_memcpy(&u, &h, 2); return u;
}

// async global->LDS DMA, 16B per lane. LDS dest = wave-uniform base + lane*16.
__device__ __forceinline__ void dma16(const void* g, void* l) {
  __builtin_amdgcn_global_load_lds(
      (const __attribute__((address_space(1))) uint32*)g,
      (__attribute__((address_space(3))) uint32*)l, 16, 0, 0);
}

// z2-partial packing into the TWO dead 1024-elem K/V column ranges per QKV
// row (b=0: elems 0..1023, b=1: elems 3072..4095).  Capacity 2048*2048 >=
// 80*64*512; never touches live Q columns (64B-line aligned split).
__device__ __forceinline__ size_t op2_addr(size_t o2) {
  return (o2 >> 11) * QROW + (o2 & 1023) + ((o2 >> 10) & 1) * 3072;
}

// ==== fused: weights f32 -> bf16 frag-order + bias concat | LN(x) -> Hf =====
__global__ __launch_bounds__(256) void misc0(
    const float* __restrict__ wk, const float* __restrict__ wv,
    const float* __restrict__ wq, const float* __restrict__ wo,
    const float* __restrict__ w1, const float* __restrict__ w2,
    const float* __restrict__ bk, const float* __restrict__ bv,
    const float* __restrict__ bq,
    __hip_bfloat16* __restrict__ out, float* __restrict__ bc,
    const float* __restrict__ x, const float* __restrict__ g0,
    const float* __restrict__ b0, __hip_bfloat16* __restrict__ Hf)
{
  if (blockIdx.x < 771) {
    int u = blockIdx.x * 256 + threadIdx.x;      // 0 .. 197375
    if (u < 196608) {
      int lane = u & 63, col = lane & 15, quad = lane >> 4;
      const float* srcrow;
      if (u < 98304) {                           // QKV: N=3072, K=256, Kch=8
        int n16 = u >> 9, kc = (u >> 6) & 7;
        int n = n16 * 16 + col;
        const float* m = (n < 512) ? (wk + (size_t)n * 256)
                       : (n < 1024) ? (wv + (size_t)(n - 512) * 256)
                                    : (wq + (size_t)(n - 1024) * 256);
        srcrow = m + kc * 32 + quad * 8;
      } else if (u < 163840) {                   // wo: N=256, K=2048, Kch=64
        int local = u - 98304;
        int n16 = local >> 12, kc = (local >> 6) & 63;
        srcrow = wo + (size_t)(n16 * 16 + col) * 2048 + kc * 32 + quad * 8;
      } else if (u < 180224) {                   // w1: N=512, K=256, Kch=8
        int local = u - 163840;
        int n16 = local >> 9, kc = (local >> 6) & 7;
        srcrow = w1 + (size_t)(n16 * 16 + col) * 256 + kc * 32 + quad * 8;
      } else {                                   // w2: N=256, K=512, Kch=16
        int local = u - 180224;
        int n16 = local >> 10, kc = (local >> 6) & 15;
        srcrow = w2 + (size_t)(n16 * 16 + col) * 512 + kc * 32 + quad * 8;
      }
      float4 a = *(const float4*)srcrow;
      float4 b = *(const float4*)(srcrow + 4);
      uint4 st;
      st.x = pack2(a.x, a.y); st.y = pack2(a.z, a.w);
      st.z = pack2(b.x, b.y); st.w = pack2(b.z, b.w);
      *(uint4*)((ushort*)out + (size_t)u * 8) = st;
    } else {
      int bu = u - 196608;                       // 0..767 bias concat [bk;bv;bq]
      const float* src; int loc;
      if      (bu < 128) { src = bk; loc = bu; }
      else if (bu < 256) { src = bv; loc = bu - 128; }
      else               { src = bq; loc = bu - 256; }
      *(float4*)(bc + 4 * (size_t)bu) = *(const float4*)(src + 4 * (size_t)loc);
    }
  } else {
    int wave = threadIdx.x >> 6, lane = threadIdx.x & 63;
    int row = (blockIdx.x - 771) * 4 + wave;
    size_t base = (size_t)row * DIM + lane * 4;
    float4 v = *(const float4*)(x + base);
    float s  = v.x + v.y + v.z + v.w;
    float s2 = v.x*v.x + v.y*v.y + v.z*v.z + v.w*v.w;
    #pragma unroll
    for (int o = 1; o < 64; o <<= 1) {
      s  += __shfl_xor(s, o);
      s2 += __shfl_xor(s2, o);
    }
    float m = s * (1.0f / DIM);
    float rb = rsqrtf(s2 * (1.0f / DIM) - m * m + 1e-5f);
    float4 gm = *(const float4*)(g0 + lane * 4);
    float4 bt = *(const float4*)(b0 + lane * 4);
    uint2 st;
    st.x = pack2((v.x - m) * rb * gm.x + bt.x, (v.y - m) * rb * gm.y + bt.y);
    st.y = pack2((v.z - m) * rb * gm.z + bt.z, (v.w - m) * rb * gm.w + bt.w);
    int kc = lane >> 3, quad = (lane >> 1) & 3, jj = 4 * (lane & 1);
    int cid = (row >> 4) * 8 + kc;
    *(uint2*)((ushort*)Hf + (size_t)cid * 512 + (quad * 16 + (row & 15)) * 8 + jj) = st;
  }
}

// ==== fused: K-LN -> Kf (frag order) | Q-LN in place | V swizzle -> Vf ======
__global__ __launch_bounds__(256) void ln_swz(
    __hip_bfloat16* __restrict__ QKV,
    const float* __restrict__ gamma, const float* __restrict__ beta,
    __hip_bfloat16* __restrict__ Kf, __hip_bfloat16* __restrict__ Vf)
{
  int j = blockIdx.x;
  if (j < 10240) {
    int wave = threadIdx.x >> 6, lane = threadIdx.x & 63;
    int idx = j * 4 + wave;                      // <8192: K ; else Q
    size_t base;
    if (idx < 8192) base = (size_t)(idx >> 1) * NQKV + (idx & 1) * DIM;
    else {
      int qi = idx - 8192;
      base = (size_t)(qi >> 3) * NQKV + 2 * NG * DIM + (qi & 7) * DIM;
    }
    __hip_bfloat16* p = QKV + base + lane * 4;
    uint2 u = *(const uint2*)p;
    float v0 = bflo(u.x), v1 = bfhi(u.x), v2 = bflo(u.y), v3 = bfhi(u.y);
    float s  = v0 + v1 + v2 + v3;
    float s2 = v0*v0 + v1*v1 + v2*v2 + v3*v3;
    #pragma unroll
    for (int o = 1; o < 64; o <<= 1) {
      s  += __shfl_xor(s, o);
      s2 += __shfl_xor(s2, o);
    }
    float m = s * (1.0f / DIM);
    float rb = rsqrtf(s2 * (1.0f / DIM) - m * m + 1e-5f);
    float4 gm = *(const float4*)(gamma + lane * 4);
    float4 bt = *(const float4*)(beta + lane * 4);
    uint2 st;
    st.x = pack2((v0 - m) * rb * gm.x + bt.x, (v1 - m) * rb * gm.y + bt.y);
    st.y = pack2((v2 - m) * rb * gm.z + bt.z, (v3 - m) * rb * gm.w + bt.w);
    if (idx < 8192) {
      int r = idx >> 1, gg = idx & 1;
      int t = r >> 1, b = r & 1;
      int bg = b * NG + gg;
      int kt = t >> 5, tr = t & 31, tc = tr >> 4, col = tr & 15;
      int ks = lane >> 3, quad = (lane >> 1) & 3, jj = 4 * (lane & 1);
      int cid = (bg * 64 + kt) * 16 + tc * 8 + ks;
      *(uint2*)((ushort*)Kf + (size_t)cid * 512 + (quad * 16 + col) * 8 + jj) = st;
    } else {
      *(uint2*)p = st;
    }
  } else {
    __shared__ ushort T[64][72];
    int vb = j - 10240;                          // 0..2047
    int t0 = (vb & 31) * 64, d0 = ((vb >> 5) & 3) * 64, bg = vb >> 7;
    int b = bg >> 1, g = bg & 1;
    int tid = threadIdx.x;
    int tr = tid >> 2, c4 = (tid & 3) * 16;
    const ushort* src = (const ushort*)QKV + ((size_t)(t0 + tr) * BSZ + b) * NQKV
                      + NG * DIM + g * DIM + d0 + c4;
    uint4 a0 = *(const uint4*)src;
    uint4 a1 = *(const uint4*)(src + 8);
    *(uint4*)&T[tr][c4]     = a0;
    *(uint4*)&T[tr][c4 + 8] = a1;
    __syncthreads();
    #pragma unroll
    for (int k2 = 0; k2 < 2; ++k2) {
      int u = tid * 2 + k2;                      // (tt,di,quad,col)
      int tt = u >> 8, di = (u >> 6) & 3, qd = (u >> 4) & 3, cl = u & 15;
      ushort tmp[8];
      #pragma unroll
      for (int e = 0; e < 8; ++e) tmp[e] = T[tt * 32 + qd * 8 + e][di * 16 + cl];
      int kt = (t0 >> 5) + tt;
      int dc = (d0 >> 4) + di;
      *(uint4*)((ushort*)Vf + (((size_t)(bg * 64 + kt) * 16 + dc) << 9) + (qd * 16 + cl) * 8)
          = *(uint4*)tmp;
    }
  }
}

// ------ MFMA GEMM: C = A * Wf(frag-order)^T (+bias)(+resid)(relu) -----------
// AFRAG: 1 = A pre-swizzled fragment-order (contiguous 1KB DMA), 0 = row-major.
// OUTMODE: 0 bf16 row-major, 1 f32 row-major, 2 f32 raw partial (split-K),
//          3 bf16 A-frag order (for next GEMM), 4 bf16 raw partial (split-K).
// GM: M-tile rows (128 or 64).  R20: GM=64 for the small GN=64 GEMMs doubles
// the grid (2-4 blocks/CU, was 1-2) -> inter-block overlap of barrier drains
// (these kernels have kiters 8-16 and are latency-bound, not issue-bound).
template<int GN, int RELU, int OUTMODE, int AFRAG, int GM>
__global__ __launch_bounds__(256) void gemm_mfma(
    const __hip_bfloat16* __restrict__ A,
    const __hip_bfloat16* __restrict__ W,
    const float* __restrict__ bias,
    const float* __restrict__ resid,
    void* __restrict__ outp,
    int M, int N, int K)
{
  constexpr int WCH = GN / 16;                       // W chunks per tile
  constexpr int ACH = GM / 16;                       // A chunks per tile
  constexpr int MC  = (GN == 128) ? (GM / 32) : (GM / 64);
  __shared__ __align__(16) ushort AS[2][ACH * 512];
  __shared__ __align__(16) ushort WS[2][WCH * 512];

  const int tid = threadIdx.x;
  const int wave = tid >> 6, lane = tid & 63;
  const int col = lane & 15, quad = lane >> 4;
  const int wm = (GN == 128) ? (wave >> 1) : wave;
  const int wn = (GN == 128) ? (wave & 1) : 0;
  const int bn0 = blockIdx.x * GN;
  const int bm0 = blockIdx.y * GM;
  const bool SPLIT = (OUTMODE == 2 || OUTMODE == 4);
  const int Keff  = SPLIT ? (K / gridDim.z) : K;
  const int kbase = SPLIT ? blockIdx.z * Keff : 0;
  const int kiters = Keff >> 5;

  f32x4 acc[MC][4];
  #pragma unroll
  for (int mc = 0; mc < MC; ++mc)
    #pragma unroll
    for (int nc = 0; nc < 4; ++nc)
      acc[mc][nc] = (f32x4){0.f, 0.f, 0.f, 0.f};

  auto stage = [&](int it, int bufi) {
    int k0 = kbase + it * 32;
    #pragma unroll
    for (int c = 0; c < ACH / 4; ++c) {
      int ch = wave * (ACH / 4) + c;
      if (AFRAG)
        dma16((const ushort*)A + ((((size_t)(bm0 >> 4) + ch) * (K >> 5) + (k0 >> 5)) << 9) + lane * 8,
              &AS[bufi][ch * 512]);
      else
        dma16((const ushort*)A + (size_t)(bm0 + ch * 16 + col) * K + k0 + quad * 8,
              &AS[bufi][ch * 512]);
    }
    #pragma unroll
    for (int c = 0; c < WCH / 4; ++c) {
      int ch = wave * (WCH / 4) + c;
      dma16((const ushort*)W + (((size_t)((bn0 >> 4) + ch) * (K >> 5) + (k0 >> 5)) << 9) + lane * 8,
            &WS[bufi][ch * 512]);
    }
  };

  stage(0, 0);
  for (int it = 0; it < kiters; ++it) {
    int cur = it & 1;
    __syncthreads();
    if (it + 1 < kiters) stage(it + 1, 1 - cur);
    short8 af[MC], bf_[4];
    #pragma unroll
    for (int mc = 0; mc < MC; ++mc)
      af[mc] = *(const short8*)&AS[cur][(wm * MC + mc) * 512 + lane * 8];
    #pragma unroll
    for (int nc = 0; nc < 4; ++nc)
      bf_[nc] = *(const short8*)&WS[cur][(wn * 4 + nc) * 512 + lane * 8];
    #pragma unroll
    for (int mc = 0; mc < MC; ++mc)
      #pragma unroll
      for (int nc = 0; nc < 4; ++nc)
        acc[mc][nc] = __builtin_amdgcn_mfma_f32_16x16x32_bf16(af[mc], bf_[nc], acc[mc][nc], 0, 0, 0);
  }

  #pragma unroll
  for (int nc = 0; nc < 4; ++nc) {
    int n = bn0 + wn * 64 + nc * 16 + col;
    float bv = 0.f;
    if (OUTMODE == 0 || OUTMODE == 1 || OUTMODE == 3) bv = bias[n];
    #pragma unroll
    for (int mc = 0; mc < MC; ++mc) {
      #pragma unroll
      for (int reg = 0; reg < 4; ++reg) {
        int m = bm0 + wm * (MC * 16) + mc * 16 + quad * 4 + reg;
        float v = acc[mc][nc][reg] + bv;
        if ((OUTMODE == 0 || OUTMODE == 1 || OUTMODE == 3) && resid)
          v += resid[(size_t)m * N + n];
        if (RELU) v = fmaxf(v, 0.f);
        if (OUTMODE == 0)
          ((__hip_bfloat16*)outp)[(size_t)m * N + n] = __float2bfloat16(v);
        else if (OUTMODE == 1)
          ((float*)outp)[(size_t)m * N + n] = v;
        else if (OUTMODE == 2)
          ((float*)outp)[(size_t)blockIdx.z * M * N + (size_t)m * N + n] = v;
        else if (OUTMODE == 3) {
          int cid = (m >> 4) * (N >> 5) + (n >> 5);
          int kl = n & 31;
          ((ushort*)outp)[(size_t)cid * 512 + ((kl >> 3) * 16 + (m & 15)) * 8 + (kl & 7)] = bf16bits(v);
        } else {  // 4: bf16 raw partial
          ((ushort*)outp)[(size_t)blockIdx.z * M * N + (size_t)m * N + n] = bf16bits(v);
        }
      }
    }
  }
}

// ---- combine: out = P[0] + P[1] (bf16 partials) + bias + resid (f32) -------
__global__ __launch_bounds__(256) void combine2(
    const ushort* __restrict__ P, const float* __restrict__ bias,
    const float* __restrict__ resid, float* __restrict__ out, int MN)
{
  int i4 = (blockIdx.x * 256 + threadIdx.x) * 4;
  uint2 a = *(const uint2*)(P + i4);
  uint2 b = *(const uint2*)(P + MN + i4);
  float4 r = *(const float4*)(resid + i4);
  float4 bb = *(const float4*)(bias + (i4 & (DIM - 1)));
  float4 o;
  o.x = bflo(a.x) + bflo(b.x) + r.x + bb.x;
  o.y = bfhi(a.x) + bfhi(b.x) + r.y + bb.y;
  o.z = bflo(a.y) + bflo(b.y) + r.z + bb.z;
  o.w = bfhi(a.y) + bfhi(b.y) + r.w + bb.w;
  *(float4*)(out + i4) = o;
}

// ---- combine 4 bf16 split-K partials + bias + resid -> X2 (f32), LN -> H2f -
__global__ __launch_bounds__(256) void combine_ln4(
    const ushort* __restrict__ P, const float* __restrict__ bias,
    const float* __restrict__ resid, float* __restrict__ X2,
    const float* __restrict__ gamma, const float* __restrict__ beta,
    __hip_bfloat16* __restrict__ H2f)
{
  const int MN = ROWS * DIM;
  int wave = threadIdx.x >> 6, lane = threadIdx.x & 63;
  int row = blockIdx.x * 4 + wave;
  size_t i = (size_t)row * DIM + lane * 4;
  uint2 a = *(const uint2*)(P + i);
  uint2 b = *(const uint2*)(P + MN + i);
  uint2 c = *(const uint2*)(P + 2 * (size_t)MN + i);
  uint2 d = *(const uint2*)(P + 3 * (size_t)MN + i);
  float4 r = *(const float4*)(resid + i);
  float4 bb = *(const float4*)(bias + lane * 4);
  float4 v;
  v.x = bflo(a.x) + bflo(b.x) + bflo(c.x) + bflo(d.x) + r.x + bb.x;
  v.y = bfhi(a.x) + bfhi(b.x) + bfhi(c.x) + bfhi(d.x) + r.y + bb.y;
  v.z = bflo(a.y) + bflo(b.y) + bflo(c.y) + bflo(d.y) + r.z + bb.z;
  v.w = bfhi(a.y) + bfhi(b.y) + bfhi(c.y) + bfhi(d.y) + r.w + bb.w;
  *(float4*)(X2 + i) = v;
  float s  = v.x + v.y + v.z + v.w;
  float s2 = v.x*v.x + v.y*v.y + v.z*v.z + v.w*v.w;
  #pragma unroll
  for (int o = 1; o < 64; o <<= 1) {
    s  += __shfl_xor(s, o);
    s2 += __shfl_xor(s2, o);
  }
  float m = s * (1.0f / DIM);
  float rb = rsqrtf(s2 * (1.0f / DIM) - m * m + 1e-5f);
  float4 gm = *(const float4*)(gamma + lane * 4);
  float4 bt = *(const float4*)(beta + lane * 4);
  uint2 st;
  st.x = pack2((v.x - m) * rb * gm.x + bt.x, (v.y - m) * rb * gm.y + bt.y);
  st.y = pack2((v.z - m) * rb * gm.z + bt.z, (v.w - m) * rb * gm.w + bt.w);
  int kc = lane >> 3, quad = (lane >> 1) & 3, jj = 4 * (lane & 1);
  int cid = (row >> 4) * 8 + kc;
  *(uint2*)((ushort*)H2f + (size_t)cid * 512 + (quad * 16 + (row & 15)) * 8 + jj) = st;
}

// ------------- MFMA causal flash attention, 16 heads, D=256 -----------------
// R20 attn == R6/R9 (measured best, reproduced: attn ~72.6us).  8-wave x
// 16-rows/wave, swapped QK^T + in-register P transpose, K+V double-buffered
// LDS, 4 waves/SIMD.  Balanced 512-block schedule, heads {x8,x8+8} per XCD.
// Shelved: Q-LN fusion (spills both reg budgets, R4/R8), V-from-L2 (R7),
// 4x32 waves (R5).  Partials: z=0 -> Obf, z=1 -> Op1f, z=2 -> dead QKV cols.
__constant__ int C_NIT[32] = {22,22,22,21,21,20,20,20,20,20,20,19,19,18,18,18,18,17,17,16,16,16,16,16,16,14,14,12,12,12, 8, 4};
__constant__ int C_QB [32] = {10,10,15,15,15, 4, 9, 9,14,14,14,13,13,13, 8, 8,12,12,12, 3, 7, 7,11,11,11, 6, 6, 2, 5, 5, 1, 0};
__constant__ int C_Z  [32] = { 0, 1, 0, 1, 2, 0, 0, 1, 0, 1, 2, 0, 1, 2, 0, 1, 0, 1, 2, 0, 0, 1, 0, 1, 2, 0, 1, 0, 0, 1, 0, 0};
__constant__ int C_K0 [32] = { 0,22, 0,22,43, 0, 0,20, 0,20,40, 0,19,38, 0,18, 0,18,35, 0, 0,16, 0,16,32, 0,14, 0, 0,12, 0, 0};
__constant__ int C_SP [32] = { 1, 1, 1, 1, 1, 0, 1, 1, 1, 1, 1, 1, 1, 1, 1, 1, 1, 1, 1, 0, 1, 1, 1, 1, 1, 1, 1, 0, 1, 1, 0, 0};

__global__ __launch_bounds__(512, 4) void attn_mfma(
    const __hip_bfloat16* QKV,               // Q read here (LN'd by ln_swz)
    const __hip_bfloat16* __restrict__ Kf,   // [bg][64 kt][16 nk][512]
    const __hip_bfloat16* __restrict__ Vf,   // [bg][64 kt][16 dc][512]
    __hip_bfloat16* __restrict__ Obf,        // frag-order [256 m16][64 kc][512]
    __hip_bfloat16* __restrict__ Op1f,       // frag-order z1 partials (m16-80)
    ushort* Op2q,                            // z2 partials in dead QKV K/V cols
    float* __restrict__ Lp)                  // [3][2048][16]
{
  __shared__ __align__(16) ushort KS[2][8192];
  __shared__ __align__(16) ushort VS[2][8192];

  const int tid  = threadIdx.x;
  const int wave = tid >> 6, lane = tid & 63;
  const int col  = lane & 15, quad = lane >> 4;

  const int bid = blockIdx.x;                // 0..511
  const int x8 = bid & 7, j = bid >> 3;      // xcd, local arrival order 0..63
  const int a = j >> 1, odd = j & 1;
  int rank;
  if (a < 16) rank = odd ? (31 - a) : a;
  else        rank = odd ? (a - 16) : (31 - (a - 16));
  const int head = odd * 8 + x8;             // heads {x8, x8+8} per XCD
  const int qb  = C_QB[rank];
  const int z   = C_Z[rank];
  const int nit = C_NIT[rank];
  const int k0  = C_K0[rank];
  const int split = C_SP[rank];

  const int b = head >> 3, hq = head & 7, g = hq >> 2;
  const int bg = b * NG + g;
  const int qw0 = qb * 128 + wave * 16;      // 16 rows per wave, 8 waves

  short8 qf[8];
  {
    int s = qw0 + col;
    const ushort* qp = (const ushort*)QKV + (size_t)s * QROW + b * NQKV
                     + 2 * NG * DIM + hq * DIM + quad * 8;
    #pragma unroll
    for (int ks = 0; ks < 8; ++ks)
      qf[ks] = *(const short8*)(qp + ks * 32);
  }

  short8 onesf;
  #pragma unroll
  for (int i = 0; i < 8; ++i) onesf[i] = (short)0x3F80;

  f32x4 o[16];
  #pragma unroll
  for (int dc = 0; dc < 16; ++dc)
    o[dc] = (f32x4){0.f, 0.f, 0.f, 0.f};
  float l_s[4] = {0.f, 0.f, 0.f, 0.f};

  auto stage = [&](int i, int bufi) {
    int kt = k0 + i;
    const ushort* kb = (const ushort*)Kf + (((size_t)bg * 64 + kt) << 13);
    const ushort* vb = (const ushort*)Vf + (((size_t)bg * 64 + kt) << 13);
    #pragma unroll
    for (int cc = 0; cc < 2; ++cc) {
      int nk = wave * 2 + cc;
      dma16(kb + (nk << 9) + lane * 8, &KS[bufi][nk * 512]);
      dma16(vb + (nk << 9) + lane * 8, &VS[bufi][nk * 512]);
    }
  };

  // shfl source lanes for the in-register P transpose:
  const int sig0 = col + 16 * ((quad & 1) * 2);   // dwords 0,1
  const int sig1 = sig0 + 16;                     // dwords 2,3

  stage(0, 0);
  for (int i = 0; i < nit; ++i) {
    int cur = i & 1;
    __syncthreads();
    if (i + 1 < nit) stage(i + 1, 1 - cur);
    int kt = k0 + i;
    if (kt * 32 > qw0 + 15) continue;

    f32x4 sf[2];
    sf[0] = (f32x4){0.f, 0.f, 0.f, 0.f};
    sf[1] = (f32x4){0.f, 0.f, 0.f, 0.f};
    __builtin_amdgcn_s_setprio(1);
    #pragma unroll
    for (int ks = 0; ks < 8; ++ks) {
      short8 kb0 = *(const short8*)&KS[cur][ks * 512 + lane * 8];
      short8 kb1 = *(const short8*)&KS[cur][(8 + ks) * 512 + lane * 8];
      // swapped: A = K (M = t), B = Q (N = s)
      sf[0] = __builtin_amdgcn_mfma_f32_16x16x32_bf16(kb0, qf[ks], sf[0], 0, 0, 0);
      sf[1] = __builtin_amdgcn_mfma_f32_16x16x32_bf16(kb1, qf[ks], sf[1], 0, 0, 0);
    }
    __builtin_amdgcn_s_setprio(0);

    // C layout (swapped): lane holds s = col, t = quad*4+reg (+tc*16)
    const bool dm = (kt * 32 + 31) > qw0;
    uint32 PK[2][2];                         // [tc][h]: t = tc*16+quad*4+2h+{0,1}
    #pragma unroll
    for (int tc = 0; tc < 2; ++tc) {
      float p[4];
      #pragma unroll
      for (int reg = 0; reg < 4; ++reg) {
        p[reg] = __expf(sf[tc][reg] * 0.0625f);
        if (dm) {
          int tg = kt * 32 + tc * 16 + quad * 4 + reg;
          int sg = qw0 + col;
          if (tg > sg) p[reg] = 0.f;
        }
      }
      PK[tc][0] = pack2(p[0], p[1]);
      PK[tc][1] = pack2(p[2], p[3]);
    }

    // assemble PV A-operand in-register: dword dw = t {quad*8+2dw, +1}
    short8 pa;
    {
      union { uint32 u[4]; short8 s8; } cvt;
      #pragma unroll
      for (int dw = 0; dw < 4; ++dw) {
        int src = (dw < 2) ? sig0 : sig1;
        uint32 a0 = (uint32)__shfl((int)PK[0][dw & 1], src, 64);
        uint32 a1 = (uint32)__shfl((int)PK[1][dw & 1], src, 64);
        cvt.u[dw] = (quad < 2) ? a0 : a1;
      }
      pa = cvt.s8;
    }

    __builtin_amdgcn_s_setprio(1);
    f32x4 zz = (f32x4){0.f, 0.f, 0.f, 0.f};
    f32x4 ps = __builtin_amdgcn_mfma_f32_16x16x32_bf16(pa, onesf, zz, 0, 0, 0);
    #pragma unroll
    for (int r = 0; r < 4; ++r) l_s[r] += ps[r];

    #pragma unroll
    for (int dc = 0; dc < 16; ++dc) {
      short8 vb = *(const short8*)&VS[cur][dc * 512 + lane * 8];
      o[dc] = __builtin_amdgcn_mfma_f32_16x16x32_bf16(pa, vb, o[dc], 0, 0, 0);
    }
    __builtin_amdgcn_s_setprio(0);
  }

  // ---- epilogue: write in A-fragment order ----
  const int colh = col >> 3, coll = col & 7;
  #pragma unroll
  for (int reg = 0; reg < 4; ++reg) {
    int s = qw0 + quad * 4 + reg;
    int m = s * BSZ + b;
    int m16 = m >> 4, ml = m & 15;
    if (!split) {
      float inv = 1.0f / l_s[reg];
      #pragma unroll
      for (int dc = 0; dc < 16; ++dc) {
        int cid = m16 * 64 + hq * 8 + (dc >> 1);
        int qt = (dc & 1) * 2 + colh;
        Obf[(size_t)cid * 512 + (qt * 16 + ml) * 8 + coll] =
            __float2bfloat16(o[dc][reg] * inv);
      }
    } else {
      #pragma unroll
      for (int dc = 0; dc < 16; ++dc) {
        int qt = (dc & 1) * 2 + colh;
        int el = (qt * 16 + ml) * 8 + coll;
        float v = o[dc][reg];
        if (z == 0) {
          Obf[((size_t)(m16 * 64 + hq * 8 + (dc >> 1))) * 512 + el] = __float2bfloat16(v);
        } else if (z == 1) {
          Op1f[((size_t)((m16 - 80) * 64 + hq * 8 + (dc >> 1))) * 512 + el] = __float2bfloat16(v);
        } else {
          size_t o2 = ((size_t)((m16 - 176) * 64 + hq * 8 + (dc >> 1))) * 512 + el;
          Op2q[op2_addr(o2)] = bf16bits(v);
        }
      }
      if (col == 0) Lp[((size_t)z * 2048 + s) * 16 + head] = l_s[reg];
    }
  }
}

// ---- merge split partials (frag space, coalesced): 2- or 3-way -------------
// rows m16 in [80,256): Obf += Op1f (+ Op2 for m16>=176), / (l0+l1(+l2)).
__global__ __launch_bounds__(256) void attn_norm(
    __hip_bfloat16* __restrict__ Obf, const __hip_bfloat16* __restrict__ Op1f,
    const ushort* __restrict__ Op2q, const float* __restrict__ Lp)
{
  int i8 = blockIdx.x * 256 + threadIdx.x;   // over 176*64*64 = 720896
  int cidr = i8 >> 6;                        // (m16r*64 + kc)
  int lane = i8 & 63;
  int m16r = cidr >> 6, kc = cidr & 63;
  int m16 = m16r + 80;
  int m = m16 * 16 + (lane & 15);
  int k = kc * 32 + (lane >> 4) * 8;
  int s = m >> 1, b = m & 1, hq = k >> 8;
  int head = b * 8 + hq;
  float l = Lp[(size_t)s * 16 + head] + Lp[(size_t)(2048 + s) * 16 + head];
  ushort* a = (ushort*)Obf + (((size_t)m16 * 64 + kc) << 9) + lane * 8;
  const ushort* c = (const ushort*)Op1f + (((size_t)m16r * 64 + kc) << 9) + lane * 8;
  uint4 ua = *(const uint4*)a;
  uint4 uc = *(const uint4*)c;
  float v0 = bflo(ua.x) + bflo(uc.x), v1 = bfhi(ua.x) + bfhi(uc.x);
  float v2 = bflo(ua.y) + bflo(uc.y), v3 = bfhi(ua.y) + bfhi(uc.y);
  float v4 = bflo(ua.z) + bflo(uc.z), v5 = bfhi(ua.z) + bfhi(uc.z);
  float v6 = bflo(ua.w) + bflo(uc.w), v7 = bfhi(ua.w) + bfhi(uc.w);
  if (s >= 1408) {                           // qb >= 11: 3-way (block-uniform)
    l += Lp[(size_t)(4096 + s) * 16 + head];
    size_t o2 = (((size_t)(m16 - 176) * 64 + kc) << 9) + lane * 8;
    uint4 ue = *(const uint4*)(Op2q + op2_addr(o2));
    v0 += bflo(ue.x); v1 += bfhi(ue.x);
    v2 += bflo(ue.y); v3 += bfhi(ue.y);
    v4 += bflo(ue.z); v5 += bfhi(ue.z);
    v6 += bflo(ue.w); v7 += bfhi(ue.w);
  }
  float inv = 1.0f / l;
  uint4 st;
  st.x = pack2(v0 * inv, v1 * inv);
  st.y = pack2(v2 * inv, v3 * inv);
  st.z = pack2(v4 * inv, v5 * inv);
  st.w = pack2(v6 * inv, v7 * inv);
  *(uint4*)a = st;
}

// ---------------------------------------------------------------------------
extern "C" void kernel_launch(void* const* d_in, const int* in_sizes, int n_in,
                              void* d_out, int out_size, void* d_ws, size_t ws_size,
                              hipStream_t stream)
{
  const float* x   = (const float*)d_in[0];
  const float* g0  = (const float*)d_in[1];
  const float* b0  = (const float*)d_in[2];
  const float* g1  = (const float*)d_in[3];
  const float* b1  = (const float*)d_in[4];
  const float* gn  = (const float*)d_in[5];
  const float* bn  = (const float*)d_in[6];
  const float* wk  = (const float*)d_in[7];
  const float* bk  = (const float*)d_in[8];
  const float* wv  = (const float*)d_in[9];
  const float* bv  = (const float*)d_in[10];
  const float* wq  = (const float*)d_in[11];
  const float* bq  = (const float*)d_in[12];
  const float* wo  = (const float*)d_in[13];
  const float* bo  = (const float*)d_in[14];
  const float* w1  = (const float*)d_in[15];
  const float* bf1 = (const float*)d_in[16];
  const float* w2  = (const float*)d_in[17];
  const float* bf2 = (const float*)d_in[18];

  char* ws = (char*)d_ws;
  const size_t MB = 1024 * 1024;
  __hip_bfloat16* QKV = (__hip_bfloat16*)(ws);            // 24MB [K/V cols dead after ln_swz -> hold z2 partials]
  __hip_bfloat16* Pwo = (__hip_bfloat16*)(ws);            //  8MB bf16 partials [after attn]
  __hip_bfloat16* Pw2 = (__hip_bfloat16*)(ws + 8  * MB);  //  4MB bf16 partials [after attn]
  float*          X2  = (float*)         (ws + 16 * MB);  //  4MB [after attn]
  __hip_bfloat16* H2f = (__hip_bfloat16*)(ws + 20 * MB);  //  2MB [after attn]
  __hip_bfloat16* F1f = (__hip_bfloat16*)(ws + 22 * MB);  //  4MB [after attn]
  __hip_bfloat16* Hf  = (__hip_bfloat16*)(ws + 24 * MB);  //  2MB [dead after QKV gemm]
  __hip_bfloat16* Kf  = (__hip_bfloat16*)(ws + 24 * MB);  //  4MB [written after Hf dead]
  __hip_bfloat16* Vf  = (__hip_bfloat16*)(ws + 28 * MB);  //  4MB
  __hip_bfloat16* Obf = (__hip_bfloat16*)(ws + 32 * MB);  // 16MB frag-order O
  __hip_bfloat16* Op1f= (__hip_bfloat16*)(ws + 48 * MB);  // 11MB z1 partials (m16 in [80,256))
  float*          BC  = (float*)         (ws + 59 * MB);  // 12KB
  float*          Lp  = (float*)         (ws + 59 * MB + 64 * 1024);  // 384KB [3][2048][16]
  __hip_bfloat16* WB  = (__hip_bfloat16*)(ws + 61 * MB);  //  3MB weights (frag order)

  __hip_bfloat16* woB = WB + 786432;
  __hip_bfloat16* w1B = WB + 1310720;
  __hip_bfloat16* w2B = WB + 1441792;

  // 0+1. weights -> frag-order bf16 + bias concat | LN(x) -> Hf (fused)
  misc0<<<1795, 256, 0, stream>>>(wk, wv, wq, wo, w1, w2, bk, bv, bq, WB, BC, x, g0, b0, Hf);
  // 2. fused K|V|Q projection (one GEMM, N=3072, frag-order A and W)
  gemm_mfma<128,0,0,1,128><<<dim3(NQKV/128, ROWS/128), 256, 0, stream>>>(Hf, WB, BC, nullptr, QKV, ROWS, NQKV, DIM);
  // 3. K-LN -> Kf | Q-LN in place | V swizzle -> Vf (fused)
  ln_swz<<<12288, 256, 0, stream>>>(QKV, gn, bn, Kf, Vf);
  // 4. attention (8-wave/16-row decomposition, 4 waves/SIMD) + merge
  attn_mfma<<<512, 512, 0, stream>>>(QKV, Kf, Vf, Obf, Op1f, (ushort*)QKV, Lp);
  attn_norm<<<2816, 256, 0, stream>>>(Obf, Op1f, (const ushort*)QKV, Lp);
  // 5. x2 = x + Obf @ wo^T + bo  (GM=64 tiles: 1024 blocks = 4/CU)
  gemm_mfma<64,0,4,1,64><<<dim3(DIM/64, ROWS/64, 4), 256, 0, stream>>>(Obf, woB, nullptr, nullptr, Pwo, ROWS, DIM, NQH*DIM);
  combine_ln4<<<ROWS / 4, 256, 0, stream>>>((const ushort*)Pwo, bo, x, X2, g1, b1, H2f);
  // 6. FFN (GM=64 tiles: 512 blocks = 2/CU each)
  gemm_mfma<64,1,3,1,64><<<dim3((2*DIM)/64, ROWS/64), 256, 0, stream>>>(H2f, w1B, bf1, nullptr, F1f, ROWS, 2*DIM, DIM);
  gemm_mfma<64,0,4,1,64><<<dim3(DIM/64, ROWS/64, 2), 256, 0, stream>>>(F1f, w2B, nullptr, nullptr, Pw2, ROWS, DIM, 2*DIM);
  combine2<<<ROWS*DIM/1024, 256, 0, stream>>>((const ushort*)Pw2, bf2, X2, (float*)d_out, ROWS*DIM);
}

// Round 11
// 235.711 us; speedup vs baseline: 1.0213x; 1.0213x over previous
//
#include <hip/hip_runtime.h>
#include <hip/hip_bf16.h>

#define SEQ  2048
#define BSZ  2
#define DIM  256
#define NG   2
#define NQH  8
#define SUBQ 4
#define ROWS (SEQ*BSZ)   // 4096
#define NQKV 3072        // fused K|V|Q projection width
#define QROW 6144        // (BSZ*NQKV) elems per s step in QKV

typedef unsigned int uint32;
typedef unsigned short ushort;
typedef __attribute__((ext_vector_type(8))) short short8;
typedef __attribute__((ext_vector_type(4))) float f32x4;

__device__ __forceinline__ float bflo(uint32 u){
  union { uint32 i; float f; } c; c.i = u << 16; return c.f;
}
__device__ __forceinline__ float bfhi(uint32 u){
  union { uint32 i; float f; } c; c.i = u & 0xffff0000u; return c.f;
}
__device__ __forceinline__ uint32 pack2(float a, float b){
  __hip_bfloat16 ha = __float2bfloat16(a);
  __hip_bfloat16 hb = __float2bfloat16(b);
  unsigned short ua, ub;
  __builtin_memcpy(&ua, &ha, 2);
  __builtin_memcpy(&ub, &hb, 2);
  return (uint32)ua | ((uint32)ub << 16);
}
__device__ __forceinline__ ushort bf16bits(float v){
  __hip_bfloat16 h = __float2bfloat16(v);
  ushort u; __builtin_memcpy(&u, &h, 2); return u;
}

// async global->LDS DMA, 16B per lane. LDS dest = wave-uniform base + lane*16.
__device__ __forceinline__ void dma16(const void* g, void* l) {
  __builtin_amdgcn_global_load_lds(
      (const __attribute__((address_space(1))) uint32*)g,
      (__attribute__((address_space(3))) uint32*)l, 16, 0, 0);
}

// z2-partial packing into the TWO dead 1024-elem K/V column ranges per QKV
// row (b=0: elems 0..1023, b=1: elems 3072..4095).  Capacity 2048*2048 >=
// 80*64*512; never touches live Q columns (64B-line aligned split).
__device__ __forceinline__ size_t op2_addr(size_t o2) {
  return (o2 >> 11) * QROW + (o2 & 1023) + ((o2 >> 10) & 1) * 3072;
}

// ==== fused: weights f32 -> bf16 frag-order + bias concat | LN(x) -> Hf =====
__global__ __launch_bounds__(256) void misc0(
    const float* __restrict__ wk, const float* __restrict__ wv,
    const float* __restrict__ wq, const float* __restrict__ wo,
    const float* __restrict__ w1, const float* __restrict__ w2,
    const float* __restrict__ bk, const float* __restrict__ bv,
    const float* __restrict__ bq,
    __hip_bfloat16* __restrict__ out, float* __restrict__ bc,
    const float* __restrict__ x, const float* __restrict__ g0,
    const float* __restrict__ b0, __hip_bfloat16* __restrict__ Hf)
{
  if (blockIdx.x < 771) {
    int u = blockIdx.x * 256 + threadIdx.x;      // 0 .. 197375
    if (u < 196608) {
      int lane = u & 63, col = lane & 15, quad = lane >> 4;
      const float* srcrow;
      if (u < 98304) {                           // QKV: N=3072, K=256, Kch=8
        int n16 = u >> 9, kc = (u >> 6) & 7;
        int n = n16 * 16 + col;
        const float* m = (n < 512) ? (wk + (size_t)n * 256)
                       : (n < 1024) ? (wv + (size_t)(n - 512) * 256)
                                    : (wq + (size_t)(n - 1024) * 256);
        srcrow = m + kc * 32 + quad * 8;
      } else if (u < 163840) {                   // wo: N=256, K=2048, Kch=64
        int local = u - 98304;
        int n16 = local >> 12, kc = (local >> 6) & 63;
        srcrow = wo + (size_t)(n16 * 16 + col) * 2048 + kc * 32 + quad * 8;
      } else if (u < 180224) {                   // w1: N=512, K=256, Kch=8
        int local = u - 163840;
        int n16 = local >> 9, kc = (local >> 6) & 7;
        srcrow = w1 + (size_t)(n16 * 16 + col) * 256 + kc * 32 + quad * 8;
      } else {                                   // w2: N=256, K=512, Kch=16
        int local = u - 180224;
        int n16 = local >> 10, kc = (local >> 6) & 15;
        srcrow = w2 + (size_t)(n16 * 16 + col) * 512 + kc * 32 + quad * 8;
      }
      float4 a = *(const float4*)srcrow;
      float4 b = *(const float4*)(srcrow + 4);
      uint4 st;
      st.x = pack2(a.x, a.y); st.y = pack2(a.z, a.w);
      st.z = pack2(b.x, b.y); st.w = pack2(b.z, b.w);
      *(uint4*)((ushort*)out + (size_t)u * 8) = st;
    } else {
      int bu = u - 196608;                       // 0..767 bias concat [bk;bv;bq]
      const float* src; int loc;
      if      (bu < 128) { src = bk; loc = bu; }
      else if (bu < 256) { src = bv; loc = bu - 128; }
      else               { src = bq; loc = bu - 256; }
      *(float4*)(bc + 4 * (size_t)bu) = *(const float4*)(src + 4 * (size_t)loc);
    }
  } else {
    int wave = threadIdx.x >> 6, lane = threadIdx.x & 63;
    int row = (blockIdx.x - 771) * 4 + wave;
    size_t base = (size_t)row * DIM + lane * 4;
    float4 v = *(const float4*)(x + base);
    float s  = v.x + v.y + v.z + v.w;
    float s2 = v.x*v.x + v.y*v.y + v.z*v.z + v.w*v.w;
    #pragma unroll
    for (int o = 1; o < 64; o <<= 1) {
      s  += __shfl_xor(s, o);
      s2 += __shfl_xor(s2, o);
    }
    float m = s * (1.0f / DIM);
    float rb = rsqrtf(s2 * (1.0f / DIM) - m * m + 1e-5f);
    float4 gm = *(const float4*)(g0 + lane * 4);
    float4 bt = *(const float4*)(b0 + lane * 4);
    uint2 st;
    st.x = pack2((v.x - m) * rb * gm.x + bt.x, (v.y - m) * rb * gm.y + bt.y);
    st.y = pack2((v.z - m) * rb * gm.z + bt.z, (v.w - m) * rb * gm.w + bt.w);
    int kc = lane >> 3, quad = (lane >> 1) & 3, jj = 4 * (lane & 1);
    int cid = (row >> 4) * 8 + kc;
    *(uint2*)((ushort*)Hf + (size_t)cid * 512 + (quad * 16 + (row & 15)) * 8 + jj) = st;
  }
}

// ==== fused: K-LN -> Kf (frag order) | Q-LN in place | V swizzle -> Vf ======
__global__ __launch_bounds__(256) void ln_swz(
    __hip_bfloat16* __restrict__ QKV,
    const float* __restrict__ gamma, const float* __restrict__ beta,
    __hip_bfloat16* __restrict__ Kf, __hip_bfloat16* __restrict__ Vf)
{
  int j = blockIdx.x;
  if (j < 10240) {
    int wave = threadIdx.x >> 6, lane = threadIdx.x & 63;
    int idx = j * 4 + wave;                      // <8192: K ; else Q
    size_t base;
    if (idx < 8192) base = (size_t)(idx >> 1) * NQKV + (idx & 1) * DIM;
    else {
      int qi = idx - 8192;
      base = (size_t)(qi >> 3) * NQKV + 2 * NG * DIM + (qi & 7) * DIM;
    }
    __hip_bfloat16* p = QKV + base + lane * 4;
    uint2 u = *(const uint2*)p;
    float v0 = bflo(u.x), v1 = bfhi(u.x), v2 = bflo(u.y), v3 = bfhi(u.y);
    float s  = v0 + v1 + v2 + v3;
    float s2 = v0*v0 + v1*v1 + v2*v2 + v3*v3;
    #pragma unroll
    for (int o = 1; o < 64; o <<= 1) {
      s  += __shfl_xor(s, o);
      s2 += __shfl_xor(s2, o);
    }
    float m = s * (1.0f / DIM);
    float rb = rsqrtf(s2 * (1.0f / DIM) - m * m + 1e-5f);
    float4 gm = *(const float4*)(gamma + lane * 4);
    float4 bt = *(const float4*)(beta + lane * 4);
    uint2 st;
    st.x = pack2((v0 - m) * rb * gm.x + bt.x, (v1 - m) * rb * gm.y + bt.y);
    st.y = pack2((v2 - m) * rb * gm.z + bt.z, (v3 - m) * rb * gm.w + bt.w);
    if (idx < 8192) {
      int r = idx >> 1, gg = idx & 1;
      int t = r >> 1, b = r & 1;
      int bg = b * NG + gg;
      int kt = t >> 5, tr = t & 31, tc = tr >> 4, col = tr & 15;
      int ks = lane >> 3, quad = (lane >> 1) & 3, jj = 4 * (lane & 1);
      int cid = (bg * 64 + kt) * 16 + tc * 8 + ks;
      *(uint2*)((ushort*)Kf + (size_t)cid * 512 + (quad * 16 + col) * 8 + jj) = st;
    } else {
      *(uint2*)p = st;
    }
  } else {
    __shared__ ushort T[64][72];
    int vb = j - 10240;                          // 0..2047
    int t0 = (vb & 31) * 64, d0 = ((vb >> 5) & 3) * 64, bg = vb >> 7;
    int b = bg >> 1, g = bg & 1;
    int tid = threadIdx.x;
    int tr = tid >> 2, c4 = (tid & 3) * 16;
    const ushort* src = (const ushort*)QKV + ((size_t)(t0 + tr) * BSZ + b) * NQKV
                      + NG * DIM + g * DIM + d0 + c4;
    uint4 a0 = *(const uint4*)src;
    uint4 a1 = *(const uint4*)(src + 8);
    *(uint4*)&T[tr][c4]     = a0;
    *(uint4*)&T[tr][c4 + 8] = a1;
    __syncthreads();
    #pragma unroll
    for (int k2 = 0; k2 < 2; ++k2) {
      int u = tid * 2 + k2;                      // (tt,di,quad,col)
      int tt = u >> 8, di = (u >> 6) & 3, qd = (u >> 4) & 3, cl = u & 15;
      ushort tmp[8];
      #pragma unroll
      for (int e = 0; e < 8; ++e) tmp[e] = T[tt * 32 + qd * 8 + e][di * 16 + cl];
      int kt = (t0 >> 5) + tt;
      int dc = (d0 >> 4) + di;
      *(uint4*)((ushort*)Vf + (((size_t)(bg * 64 + kt) * 16 + dc) << 9) + (qd * 16 + cl) * 8)
          = *(uint4*)tmp;
    }
  }
}

// ------ MFMA GEMM: C = A * Wf(frag-order)^T (+bias)(+resid)(relu) -----------
// AFRAG: 1 = A pre-swizzled fragment-order (contiguous 1KB DMA), 0 = row-major.
// OUTMODE: 0 bf16 row-major, 1 f32 row-major, 2 f32 raw partial (split-K),
//          3 bf16 A-frag order (for next GEMM), 4 bf16 raw partial (split-K).
// GM=128 fixed: R10 measured GM=64 (more blocks/CU, fewer MFMA per stage)
// as neutral-to-negative (240.7 vs 237.3) -> reverted.
template<int GN, int RELU, int OUTMODE, int AFRAG>
__global__ __launch_bounds__(256) void gemm_mfma(
    const __hip_bfloat16* __restrict__ A,
    const __hip_bfloat16* __restrict__ W,
    const float* __restrict__ bias,
    const float* __restrict__ resid,
    void* __restrict__ outp,
    int M, int N, int K)
{
  constexpr int WCH = GN / 16;
  constexpr int MC  = (GN == 128) ? 4 : 2;
  __shared__ __align__(16) ushort AS[2][4096];
  __shared__ __align__(16) ushort WS[2][WCH * 512];

  const int tid = threadIdx.x;
  const int wave = tid >> 6, lane = tid & 63;
  const int col = lane & 15, quad = lane >> 4;
  const int wm = (GN == 128) ? (wave >> 1) : wave;
  const int wn = (GN == 128) ? (wave & 1) : 0;
  const int bn0 = blockIdx.x * GN;
  const int bm0 = blockIdx.y * 128;
  const bool SPLIT = (OUTMODE == 2 || OUTMODE == 4);
  const int Keff  = SPLIT ? (K / gridDim.z) : K;
  const int kbase = SPLIT ? blockIdx.z * Keff : 0;
  const int kiters = Keff >> 5;

  f32x4 acc[MC][4];
  #pragma unroll
  for (int mc = 0; mc < MC; ++mc)
    #pragma unroll
    for (int nc = 0; nc < 4; ++nc)
      acc[mc][nc] = (f32x4){0.f, 0.f, 0.f, 0.f};

  auto stage = [&](int it, int bufi) {
    int k0 = kbase + it * 32;
    #pragma unroll
    for (int c = 0; c < 2; ++c) {
      int ch = wave * 2 + c;
      if (AFRAG)
        dma16((const ushort*)A + ((((size_t)(bm0 >> 4) + ch) * (K >> 5) + (k0 >> 5)) << 9) + lane * 8,
              &AS[bufi][ch * 512]);
      else
        dma16((const ushort*)A + (size_t)(bm0 + ch * 16 + col) * K + k0 + quad * 8,
              &AS[bufi][ch * 512]);
    }
    #pragma unroll
    for (int c = 0; c < WCH / 4; ++c) {
      int ch = wave * (WCH / 4) + c;
      dma16((const ushort*)W + (((size_t)((bn0 >> 4) + ch) * (K >> 5) + (k0 >> 5)) << 9) + lane * 8,
            &WS[bufi][ch * 512]);
    }
  };

  stage(0, 0);
  for (int it = 0; it < kiters; ++it) {
    int cur = it & 1;
    __syncthreads();
    if (it + 1 < kiters) stage(it + 1, 1 - cur);
    short8 af[MC], bf_[4];
    #pragma unroll
    for (int mc = 0; mc < MC; ++mc)
      af[mc] = *(const short8*)&AS[cur][(wm * MC + mc) * 512 + lane * 8];
    #pragma unroll
    for (int nc = 0; nc < 4; ++nc)
      bf_[nc] = *(const short8*)&WS[cur][(wn * 4 + nc) * 512 + lane * 8];
    #pragma unroll
    for (int mc = 0; mc < MC; ++mc)
      #pragma unroll
      for (int nc = 0; nc < 4; ++nc)
        acc[mc][nc] = __builtin_amdgcn_mfma_f32_16x16x32_bf16(af[mc], bf_[nc], acc[mc][nc], 0, 0, 0);
  }

  #pragma unroll
  for (int nc = 0; nc < 4; ++nc) {
    int n = bn0 + wn * 64 + nc * 16 + col;
    float bv = 0.f;
    if (OUTMODE == 0 || OUTMODE == 1 || OUTMODE == 3) bv = bias[n];
    #pragma unroll
    for (int mc = 0; mc < MC; ++mc) {
      #pragma unroll
      for (int reg = 0; reg < 4; ++reg) {
        int m = bm0 + wm * (MC * 16) + mc * 16 + quad * 4 + reg;
        float v = acc[mc][nc][reg] + bv;
        if ((OUTMODE == 0 || OUTMODE == 1 || OUTMODE == 3) && resid)
          v += resid[(size_t)m * N + n];
        if (RELU) v = fmaxf(v, 0.f);
        if (OUTMODE == 0)
          ((__hip_bfloat16*)outp)[(size_t)m * N + n] = __float2bfloat16(v);
        else if (OUTMODE == 1)
          ((float*)outp)[(size_t)m * N + n] = v;
        else if (OUTMODE == 2)
          ((float*)outp)[(size_t)blockIdx.z * M * N + (size_t)m * N + n] = v;
        else if (OUTMODE == 3) {
          int cid = (m >> 4) * (N >> 5) + (n >> 5);
          int kl = n & 31;
          ((ushort*)outp)[(size_t)cid * 512 + ((kl >> 3) * 16 + (m & 15)) * 8 + (kl & 7)] = bf16bits(v);
        } else {  // 4: bf16 raw partial
          ((ushort*)outp)[(size_t)blockIdx.z * M * N + (size_t)m * N + n] = bf16bits(v);
        }
      }
    }
  }
}

// ---- combine: out = P[0] + P[1] (bf16 partials) + bias + resid (f32) -------
__global__ __launch_bounds__(256) void combine2(
    const ushort* __restrict__ P, const float* __restrict__ bias,
    const float* __restrict__ resid, float* __restrict__ out, int MN)
{
  int i4 = (blockIdx.x * 256 + threadIdx.x) * 4;
  uint2 a = *(const uint2*)(P + i4);
  uint2 b = *(const uint2*)(P + MN + i4);
  float4 r = *(const float4*)(resid + i4);
  float4 bb = *(const float4*)(bias + (i4 & (DIM - 1)));
  float4 o;
  o.x = bflo(a.x) + bflo(b.x) + r.x + bb.x;
  o.y = bfhi(a.x) + bfhi(b.x) + r.y + bb.y;
  o.z = bflo(a.y) + bflo(b.y) + r.z + bb.z;
  o.w = bfhi(a.y) + bfhi(b.y) + r.w + bb.w;
  *(float4*)(out + i4) = o;
}

// ---- combine 4 bf16 split-K partials + bias + resid -> X2 (f32), LN -> H2f -
__global__ __launch_bounds__(256) void combine_ln4(
    const ushort* __restrict__ P, const float* __restrict__ bias,
    const float* __restrict__ resid, float* __restrict__ X2,
    const float* __restrict__ gamma, const float* __restrict__ beta,
    __hip_bfloat16* __restrict__ H2f)
{
  const int MN = ROWS * DIM;
  int wave = threadIdx.x >> 6, lane = threadIdx.x & 63;
  int row = blockIdx.x * 4 + wave;
  size_t i = (size_t)row * DIM + lane * 4;
  uint2 a = *(const uint2*)(P + i);
  uint2 b = *(const uint2*)(P + MN + i);
  uint2 c = *(const uint2*)(P + 2 * (size_t)MN + i);
  uint2 d = *(const uint2*)(P + 3 * (size_t)MN + i);
  float4 r = *(const float4*)(resid + i);
  float4 bb = *(const float4*)(bias + lane * 4);
  float4 v;
  v.x = bflo(a.x) + bflo(b.x) + bflo(c.x) + bflo(d.x) + r.x + bb.x;
  v.y = bfhi(a.x) + bfhi(b.x) + bfhi(c.x) + bfhi(d.x) + r.y + bb.y;
  v.z = bflo(a.y) + bflo(b.y) + bflo(c.y) + bflo(d.y) + r.z + bb.z;
  v.w = bfhi(a.y) + bfhi(b.y) + bfhi(c.y) + bfhi(d.y) + r.w + bb.w;
  *(float4*)(X2 + i) = v;
  float s  = v.x + v.y + v.z + v.w;
  float s2 = v.x*v.x + v.y*v.y + v.z*v.z + v.w*v.w;
  #pragma unroll
  for (int o = 1; o < 64; o <<= 1) {
    s  += __shfl_xor(s, o);
    s2 += __shfl_xor(s2, o);
  }
  float m = s * (1.0f / DIM);
  float rb = rsqrtf(s2 * (1.0f / DIM) - m * m + 1e-5f);
  float4 gm = *(const float4*)(gamma + lane * 4);
  float4 bt = *(const float4*)(beta + lane * 4);
  uint2 st;
  st.x = pack2((v.x - m) * rb * gm.x + bt.x, (v.y - m) * rb * gm.y + bt.y);
  st.y = pack2((v.z - m) * rb * gm.z + bt.z, (v.w - m) * rb * gm.w + bt.w);
  int kc = lane >> 3, quad = (lane >> 1) & 3, jj = 4 * (lane & 1);
  int cid = (row >> 4) * 8 + kc;
  *(uint2*)((ushort*)H2f + (size_t)cid * 512 + (quad * 16 + (row & 15)) * 8 + jj) = st;
}

// ------------- MFMA causal flash attention, 16 heads, D=256 -----------------
// FINAL == R6/R9 (best measured: 236.0us total, attn 72-74us; reproduced
// twice).  8-wave x 16-rows/wave, swapped QK^T + in-register P transpose,
// K+V double-buffered LDS, 4 waves/SIMD (VGPR 64 + 64 AGPR).  Balanced
// 512-block schedule (2/CU), heads {x8, x8+8} co-located per XCD,
// pairing-robust rank order.
// Measured and shelved: Q-LN fusion (scratch spills at BOTH register
// budgets: R4 at 128-VGPR baseline, R8 at 64-VGPR/128-cap baseline),
// V-from-L2 (latency serialization, 118us, R7), 4x32 wave shape (R5:
// equal, LDS-amplification vs occupancy is a wash), GM=64 small-GEMM
// tiles (R10: neutral-negative).
// Partials: z=0 -> Obf (in place), z=1 -> Op1f (m16 in [80,256)),
// z=2 -> dead K/V columns of QKV (freed after ln_swz).
__constant__ int C_NIT[32] = {22,22,22,21,21,20,20,20,20,20,20,19,19,18,18,18,18,17,17,16,16,16,16,16,16,14,14,12,12,12, 8, 4};
__constant__ int C_QB [32] = {10,10,15,15,15, 4, 9, 9,14,14,14,13,13,13, 8, 8,12,12,12, 3, 7, 7,11,11,11, 6, 6, 2, 5, 5, 1, 0};
__constant__ int C_Z  [32] = { 0, 1, 0, 1, 2, 0, 0, 1, 0, 1, 2, 0, 1, 2, 0, 1, 0, 1, 2, 0, 0, 1, 0, 1, 2, 0, 1, 0, 0, 1, 0, 0};
__constant__ int C_K0 [32] = { 0,22, 0,22,43, 0, 0,20, 0,20,40, 0,19,38, 0,18, 0,18,35, 0, 0,16, 0,16,32, 0,14, 0, 0,12, 0, 0};
__constant__ int C_SP [32] = { 1, 1, 1, 1, 1, 0, 1, 1, 1, 1, 1, 1, 1, 1, 1, 1, 1, 1, 1, 0, 1, 1, 1, 1, 1, 1, 1, 0, 1, 1, 0, 0};

__global__ __launch_bounds__(512, 4) void attn_mfma(
    const __hip_bfloat16* QKV,               // Q read here (LN'd by ln_swz)
    const __hip_bfloat16* __restrict__ Kf,   // [bg][64 kt][16 nk][512]
    const __hip_bfloat16* __restrict__ Vf,   // [bg][64 kt][16 dc][512]
    __hip_bfloat16* __restrict__ Obf,        // frag-order [256 m16][64 kc][512]
    __hip_bfloat16* __restrict__ Op1f,       // frag-order z1 partials (m16-80)
    ushort* Op2q,                            // z2 partials in dead QKV K/V cols
    float* __restrict__ Lp)                  // [3][2048][16]
{
  __shared__ __align__(16) ushort KS[2][8192];
  __shared__ __align__(16) ushort VS[2][8192];

  const int tid  = threadIdx.x;
  const int wave = tid >> 6, lane = tid & 63;
  const int col  = lane & 15, quad = lane >> 4;

  const int bid = blockIdx.x;                // 0..511
  const int x8 = bid & 7, j = bid >> 3;      // xcd, local arrival order 0..63
  const int a = j >> 1, odd = j & 1;
  int rank;
  if (a < 16) rank = odd ? (31 - a) : a;
  else        rank = odd ? (a - 16) : (31 - (a - 16));
  const int head = odd * 8 + x8;             // heads {x8, x8+8} per XCD
  const int qb  = C_QB[rank];
  const int z   = C_Z[rank];
  const int nit = C_NIT[rank];
  const int k0  = C_K0[rank];
  const int split = C_SP[rank];

  const int b = head >> 3, hq = head & 7, g = hq >> 2;
  const int bg = b * NG + g;
  const int qw0 = qb * 128 + wave * 16;      // 16 rows per wave, 8 waves

  short8 qf[8];
  {
    int s = qw0 + col;
    const ushort* qp = (const ushort*)QKV + (size_t)s * QROW + b * NQKV
                     + 2 * NG * DIM + hq * DIM + quad * 8;
    #pragma unroll
    for (int ks = 0; ks < 8; ++ks)
      qf[ks] = *(const short8*)(qp + ks * 32);
  }

  short8 onesf;
  #pragma unroll
  for (int i = 0; i < 8; ++i) onesf[i] = (short)0x3F80;

  f32x4 o[16];
  #pragma unroll
  for (int dc = 0; dc < 16; ++dc)
    o[dc] = (f32x4){0.f, 0.f, 0.f, 0.f};
  float l_s[4] = {0.f, 0.f, 0.f, 0.f};

  auto stage = [&](int i, int bufi) {
    int kt = k0 + i;
    const ushort* kb = (const ushort*)Kf + (((size_t)bg * 64 + kt) << 13);
    const ushort* vb = (const ushort*)Vf + (((size_t)bg * 64 + kt) << 13);
    #pragma unroll
    for (int cc = 0; cc < 2; ++cc) {
      int nk = wave * 2 + cc;
      dma16(kb + (nk << 9) + lane * 8, &KS[bufi][nk * 512]);
      dma16(vb + (nk << 9) + lane * 8, &VS[bufi][nk * 512]);
    }
  };

  // shfl source lanes for the in-register P transpose:
  const int sig0 = col + 16 * ((quad & 1) * 2);   // dwords 0,1
  const int sig1 = sig0 + 16;                     // dwords 2,3

  stage(0, 0);
  for (int i = 0; i < nit; ++i) {
    int cur = i & 1;
    __syncthreads();
    if (i + 1 < nit) stage(i + 1, 1 - cur);
    int kt = k0 + i;
    if (kt * 32 > qw0 + 15) continue;

    f32x4 sf[2];
    sf[0] = (f32x4){0.f, 0.f, 0.f, 0.f};
    sf[1] = (f32x4){0.f, 0.f, 0.f, 0.f};
    __builtin_amdgcn_s_setprio(1);
    #pragma unroll
    for (int ks = 0; ks < 8; ++ks) {
      short8 kb0 = *(const short8*)&KS[cur][ks * 512 + lane * 8];
      short8 kb1 = *(const short8*)&KS[cur][(8 + ks) * 512 + lane * 8];
      // swapped: A = K (M = t), B = Q (N = s)
      sf[0] = __builtin_amdgcn_mfma_f32_16x16x32_bf16(kb0, qf[ks], sf[0], 0, 0, 0);
      sf[1] = __builtin_amdgcn_mfma_f32_16x16x32_bf16(kb1, qf[ks], sf[1], 0, 0, 0);
    }
    __builtin_amdgcn_s_setprio(0);

    // C layout (swapped): lane holds s = col, t = quad*4+reg (+tc*16)
    const bool dm = (kt * 32 + 31) > qw0;
    uint32 PK[2][2];                         // [tc][h]: t = tc*16+quad*4+2h+{0,1}
    #pragma unroll
    for (int tc = 0; tc < 2; ++tc) {
      float p[4];
      #pragma unroll
      for (int reg = 0; reg < 4; ++reg) {
        p[reg] = __expf(sf[tc][reg] * 0.0625f);
        if (dm) {
          int tg = kt * 32 + tc * 16 + quad * 4 + reg;
          int sg = qw0 + col;
          if (tg > sg) p[reg] = 0.f;
        }
      }
      PK[tc][0] = pack2(p[0], p[1]);
      PK[tc][1] = pack2(p[2], p[3]);
    }

    // assemble PV A-operand in-register: dword dw = t {quad*8+2dw, +1}
    short8 pa;
    {
      union { uint32 u[4]; short8 s8; } cvt;
      #pragma unroll
      for (int dw = 0; dw < 4; ++dw) {
        int src = (dw < 2) ? sig0 : sig1;
        uint32 a0 = (uint32)__shfl((int)PK[0][dw & 1], src, 64);
        uint32 a1 = (uint32)__shfl((int)PK[1][dw & 1], src, 64);
        cvt.u[dw] = (quad < 2) ? a0 : a1;
      }
      pa = cvt.s8;
    }

    __builtin_amdgcn_s_setprio(1);
    f32x4 zz = (f32x4){0.f, 0.f, 0.f, 0.f};
    f32x4 ps = __builtin_amdgcn_mfma_f32_16x16x32_bf16(pa, onesf, zz, 0, 0, 0);
    #pragma unroll
    for (int r = 0; r < 4; ++r) l_s[r] += ps[r];

    #pragma unroll
    for (int dc = 0; dc < 16; ++dc) {
      short8 vb = *(const short8*)&VS[cur][dc * 512 + lane * 8];
      o[dc] = __builtin_amdgcn_mfma_f32_16x16x32_bf16(pa, vb, o[dc], 0, 0, 0);
    }
    __builtin_amdgcn_s_setprio(0);
  }

  // ---- epilogue: write in A-fragment order ----
  const int colh = col >> 3, coll = col & 7;
  #pragma unroll
  for (int reg = 0; reg < 4; ++reg) {
    int s = qw0 + quad * 4 + reg;
    int m = s * BSZ + b;
    int m16 = m >> 4, ml = m & 15;
    if (!split) {
      float inv = 1.0f / l_s[reg];
      #pragma unroll
      for (int dc = 0; dc < 16; ++dc) {
        int cid = m16 * 64 + hq * 8 + (dc >> 1);
        int qt = (dc & 1) * 2 + colh;
        Obf[(size_t)cid * 512 + (qt * 16 + ml) * 8 + coll] =
            __float2bfloat16(o[dc][reg] * inv);
      }
    } else {
      #pragma unroll
      for (int dc = 0; dc < 16; ++dc) {
        int qt = (dc & 1) * 2 + colh;
        int el = (qt * 16 + ml) * 8 + coll;
        float v = o[dc][reg];
        if (z == 0) {
          Obf[((size_t)(m16 * 64 + hq * 8 + (dc >> 1))) * 512 + el] = __float2bfloat16(v);
        } else if (z == 1) {
          Op1f[((size_t)((m16 - 80) * 64 + hq * 8 + (dc >> 1))) * 512 + el] = __float2bfloat16(v);
        } else {
          size_t o2 = ((size_t)((m16 - 176) * 64 + hq * 8 + (dc >> 1))) * 512 + el;
          Op2q[op2_addr(o2)] = bf16bits(v);
        }
      }
      if (col == 0) Lp[((size_t)z * 2048 + s) * 16 + head] = l_s[reg];
    }
  }
}

// ---- merge split partials (frag space, coalesced): 2- or 3-way -------------
// rows m16 in [80,256): Obf += Op1f (+ Op2 for m16>=176), / (l0+l1(+l2)).
__global__ __launch_bounds__(256) void attn_norm(
    __hip_bfloat16* __restrict__ Obf, const __hip_bfloat16* __restrict__ Op1f,
    const ushort* __restrict__ Op2q, const float* __restrict__ Lp)
{
  int i8 = blockIdx.x * 256 + threadIdx.x;   // over 176*64*64 = 720896
  int cidr = i8 >> 6;                        // (m16r*64 + kc)
  int lane = i8 & 63;
  int m16r = cidr >> 6, kc = cidr & 63;
  int m16 = m16r + 80;
  int m = m16 * 16 + (lane & 15);
  int k = kc * 32 + (lane >> 4) * 8;
  int s = m >> 1, b = m & 1, hq = k >> 8;
  int head = b * 8 + hq;
  float l = Lp[(size_t)s * 16 + head] + Lp[(size_t)(2048 + s) * 16 + head];
  ushort* a = (ushort*)Obf + (((size_t)m16 * 64 + kc) << 9) + lane * 8;
  const ushort* c = (const ushort*)Op1f + (((size_t)m16r * 64 + kc) << 9) + lane * 8;
  uint4 ua = *(const uint4*)a;
  uint4 uc = *(const uint4*)c;
  float v0 = bflo(ua.x) + bflo(uc.x), v1 = bfhi(ua.x) + bfhi(uc.x);
  float v2 = bflo(ua.y) + bflo(uc.y), v3 = bfhi(ua.y) + bfhi(uc.y);
  float v4 = bflo(ua.z) + bflo(uc.z), v5 = bfhi(ua.z) + bfhi(uc.z);
  float v6 = bflo(ua.w) + bflo(uc.w), v7 = bfhi(ua.w) + bfhi(uc.w);
  if (s >= 1408) {                           // qb >= 11: 3-way (block-uniform)
    l += Lp[(size_t)(4096 + s) * 16 + head];
    size_t o2 = (((size_t)(m16 - 176) * 64 + kc) << 9) + lane * 8;
    uint4 ue = *(const uint4*)(Op2q + op2_addr(o2));
    v0 += bflo(ue.x); v1 += bfhi(ue.x);
    v2 += bflo(ue.y); v3 += bfhi(ue.y);
    v4 += bflo(ue.z); v5 += bfhi(ue.z);
    v6 += bflo(ue.w); v7 += bfhi(ue.w);
  }
  float inv = 1.0f / l;
  uint4 st;
  st.x = pack2(v0 * inv, v1 * inv);
  st.y = pack2(v2 * inv, v3 * inv);
  st.z = pack2(v4 * inv, v5 * inv);
  st.w = pack2(v6 * inv, v7 * inv);
  *(uint4*)a = st;
}

// ---------------------------------------------------------------------------
extern "C" void kernel_launch(void* const* d_in, const int* in_sizes, int n_in,
                              void* d_out, int out_size, void* d_ws, size_t ws_size,
                              hipStream_t stream)
{
  const float* x   = (const float*)d_in[0];
  const float* g0  = (const float*)d_in[1];
  const float* b0  = (const float*)d_in[2];
  const float* g1  = (const float*)d_in[3];
  const float* b1  = (const float*)d_in[4];
  const float* gn  = (const float*)d_in[5];
  const float* bn  = (const float*)d_in[6];
  const float* wk  = (const float*)d_in[7];
  const float* bk  = (const float*)d_in[8];
  const float* wv  = (const float*)d_in[9];
  const float* bv  = (const float*)d_in[10];
  const float* wq  = (const float*)d_in[11];
  const float* bq  = (const float*)d_in[12];
  const float* wo  = (const float*)d_in[13];
  const float* bo  = (const float*)d_in[14];
  const float* w1  = (const float*)d_in[15];
  const float* bf1 = (const float*)d_in[16];
  const float* w2  = (const float*)d_in[17];
  const float* bf2 = (const float*)d_in[18];

  char* ws = (char*)d_ws;
  const size_t MB = 1024 * 1024;
  __hip_bfloat16* QKV = (__hip_bfloat16*)(ws);            // 24MB [K/V cols dead after ln_swz -> hold z2 partials]
  __hip_bfloat16* Pwo = (__hip_bfloat16*)(ws);            //  8MB bf16 partials [after attn]
  __hip_bfloat16* Pw2 = (__hip_bfloat16*)(ws + 8  * MB);  //  4MB bf16 partials [after attn]
  float*          X2  = (float*)         (ws + 16 * MB);  //  4MB [after attn]
  __hip_bfloat16* H2f = (__hip_bfloat16*)(ws + 20 * MB);  //  2MB [after attn]
  __hip_bfloat16* F1f = (__hip_bfloat16*)(ws + 22 * MB);  //  4MB [after attn]
  __hip_bfloat16* Hf  = (__hip_bfloat16*)(ws + 24 * MB);  //  2MB [dead after QKV gemm]
  __hip_bfloat16* Kf  = (__hip_bfloat16*)(ws + 24 * MB);  //  4MB [written after Hf dead]
  __hip_bfloat16* Vf  = (__hip_bfloat16*)(ws + 28 * MB);  //  4MB
  __hip_bfloat16* Obf = (__hip_bfloat16*)(ws + 32 * MB);  // 16MB frag-order O
  __hip_bfloat16* Op1f= (__hip_bfloat16*)(ws + 48 * MB);  // 11MB z1 partials (m16 in [80,256))
  float*          BC  = (float*)         (ws + 59 * MB);  // 12KB
  float*          Lp  = (float*)         (ws + 59 * MB + 64 * 1024);  // 384KB [3][2048][16]
  __hip_bfloat16* WB  = (__hip_bfloat16*)(ws + 61 * MB);  //  3MB weights (frag order)

  __hip_bfloat16* woB = WB + 786432;
  __hip_bfloat16* w1B = WB + 1310720;
  __hip_bfloat16* w2B = WB + 1441792;

  // 0+1. weights -> frag-order bf16 + bias concat | LN(x) -> Hf (fused)
  misc0<<<1795, 256, 0, stream>>>(wk, wv, wq, wo, w1, w2, bk, bv, bq, WB, BC, x, g0, b0, Hf);
  // 2. fused K|V|Q projection (one GEMM, N=3072, frag-order A and W)
  gemm_mfma<128,0,0,1><<<dim3(NQKV/128, ROWS/128), 256, 0, stream>>>(Hf, WB, BC, nullptr, QKV, ROWS, NQKV, DIM);
  // 3. K-LN -> Kf | Q-LN in place | V swizzle -> Vf (fused)
  ln_swz<<<12288, 256, 0, stream>>>(QKV, gn, bn, Kf, Vf);
  // 4. attention (8-wave/16-row decomposition, 4 waves/SIMD) + merge
  attn_mfma<<<512, 512, 0, stream>>>(QKV, Kf, Vf, Obf, Op1f, (ushort*)QKV, Lp);
  attn_norm<<<2816, 256, 0, stream>>>(Obf, Op1f, (const ushort*)QKV, Lp);
  // 5. x2 = x + Obf @ wo^T + bo  (AFRAG staging, bf16 split-K=4 partials)
  gemm_mfma<64,0,4,1><<<dim3(DIM/64, ROWS/128, 4), 256, 0, stream>>>(Obf, woB, nullptr, nullptr, Pwo, ROWS, DIM, NQH*DIM);
  combine_ln4<<<ROWS / 4, 256, 0, stream>>>((const ushort*)Pwo, bo, x, X2, g1, b1, H2f);
  // 6. FFN (w1: frag-order out; w2: AFRAG staging, bf16 split-K=2 partials)
  gemm_mfma<64,1,3,1><<<dim3((2*DIM)/64, ROWS/128), 256, 0, stream>>>(H2f, w1B, bf1, nullptr, F1f, ROWS, 2*DIM, DIM);
  gemm_mfma<64,0,4,1><<<dim3(DIM/64, ROWS/128, 2), 256, 0, stream>>>(F1f, w2B, nullptr, nullptr, Pw2, ROWS, DIM, 2*DIM);
  combine2<<<ROWS*DIM/1024, 256, 0, stream>>>((const ushort*)Pw2, bf2, X2, (float*)d_out, ROWS*DIM);
}

// Round 12
// 232.753 us; speedup vs baseline: 1.0343x; 1.0127x over previous
//
#include <hip/hip_runtime.h>
#include <hip/hip_bf16.h>

#define SEQ  2048
#define BSZ  2
#define DIM  256
#define NG   2
#define NQH  8
#define SUBQ 4
#define ROWS (SEQ*BSZ)   // 4096
#define NQKV 3072        // fused K|V|Q projection width
#define QROW 6144        // (BSZ*NQKV) elems per s step in QKV

typedef unsigned int uint32;
typedef unsigned short ushort;
typedef __attribute__((ext_vector_type(8))) short short8;
typedef __attribute__((ext_vector_type(4))) float f32x4;

__device__ __forceinline__ float bflo(uint32 u){
  union { uint32 i; float f; } c; c.i = u << 16; return c.f;
}
__device__ __forceinline__ float bfhi(uint32 u){
  union { uint32 i; float f; } c; c.i = u & 0xffff0000u; return c.f;
}
__device__ __forceinline__ uint32 pack2(float a, float b){
  __hip_bfloat16 ha = __float2bfloat16(a);
  __hip_bfloat16 hb = __float2bfloat16(b);
  unsigned short ua, ub;
  __builtin_memcpy(&ua, &ha, 2);
  __builtin_memcpy(&ub, &hb, 2);
  return (uint32)ua | ((uint32)ub << 16);
}
__device__ __forceinline__ ushort bf16bits(float v){
  __hip_bfloat16 h = __float2bfloat16(v);
  ushort u; __builtin_memcpy(&u, &h, 2); return u;
}

// async global->LDS DMA, 16B per lane. LDS dest = wave-uniform base + lane*16.
__device__ __forceinline__ void dma16(const void* g, void* l) {
  __builtin_amdgcn_global_load_lds(
      (const __attribute__((address_space(1))) uint32*)g,
      (__attribute__((address_space(3))) uint32*)l, 16, 0, 0);
}

// z2-partial packing into the TWO dead 1024-elem K/V column ranges per QKV
// row (b=0: elems 0..1023, b=1: elems 3072..4095).  Capacity 2048*2048 >=
// 80*64*512; never touches live Q columns (64B-line aligned split).
__device__ __forceinline__ size_t op2_addr(size_t o2) {
  return (o2 >> 11) * QROW + (o2 & 1023) + ((o2 >> 10) & 1) * 3072;
}

// ==== fused: weights f32 -> bf16 frag-order + bias concat | LN(x) -> Hf =====
__global__ __launch_bounds__(256) void misc0(
    const float* __restrict__ wk, const float* __restrict__ wv,
    const float* __restrict__ wq, const float* __restrict__ wo,
    const float* __restrict__ w1, const float* __restrict__ w2,
    const float* __restrict__ bk, const float* __restrict__ bv,
    const float* __restrict__ bq,
    __hip_bfloat16* __restrict__ out, float* __restrict__ bc,
    const float* __restrict__ x, const float* __restrict__ g0,
    const float* __restrict__ b0, __hip_bfloat16* __restrict__ Hf)
{
  if (blockIdx.x < 771) {
    int u = blockIdx.x * 256 + threadIdx.x;      // 0 .. 197375
    if (u < 196608) {
      int lane = u & 63, col = lane & 15, quad = lane >> 4;
      const float* srcrow;
      if (u < 98304) {                           // QKV: N=3072, K=256, Kch=8
        int n16 = u >> 9, kc = (u >> 6) & 7;
        int n = n16 * 16 + col;
        const float* m = (n < 512) ? (wk + (size_t)n * 256)
                       : (n < 1024) ? (wv + (size_t)(n - 512) * 256)
                                    : (wq + (size_t)(n - 1024) * 256);
        srcrow = m + kc * 32 + quad * 8;
      } else if (u < 163840) {                   // wo: N=256, K=2048, Kch=64
        int local = u - 98304;
        int n16 = local >> 12, kc = (local >> 6) & 63;
        srcrow = wo + (size_t)(n16 * 16 + col) * 2048 + kc * 32 + quad * 8;
      } else if (u < 180224) {                   // w1: N=512, K=256, Kch=8
        int local = u - 163840;
        int n16 = local >> 9, kc = (local >> 6) & 7;
        srcrow = w1 + (size_t)(n16 * 16 + col) * 256 + kc * 32 + quad * 8;
      } else {                                   // w2: N=256, K=512, Kch=16
        int local = u - 180224;
        int n16 = local >> 10, kc = (local >> 6) & 15;
        srcrow = w2 + (size_t)(n16 * 16 + col) * 512 + kc * 32 + quad * 8;
      }
      float4 a = *(const float4*)srcrow;
      float4 b = *(const float4*)(srcrow + 4);
      uint4 st;
      st.x = pack2(a.x, a.y); st.y = pack2(a.z, a.w);
      st.z = pack2(b.x, b.y); st.w = pack2(b.z, b.w);
      *(uint4*)((ushort*)out + (size_t)u * 8) = st;
    } else {
      int bu = u - 196608;                       // 0..767 bias concat [bk;bv;bq]
      const float* src; int loc;
      if      (bu < 128) { src = bk; loc = bu; }
      else if (bu < 256) { src = bv; loc = bu - 128; }
      else               { src = bq; loc = bu - 256; }
      *(float4*)(bc + 4 * (size_t)bu) = *(const float4*)(src + 4 * (size_t)loc);
    }
  } else {
    int wave = threadIdx.x >> 6, lane = threadIdx.x & 63;
    int row = (blockIdx.x - 771) * 4 + wave;
    size_t base = (size_t)row * DIM + lane * 4;
    float4 v = *(const float4*)(x + base);
    float s  = v.x + v.y + v.z + v.w;
    float s2 = v.x*v.x + v.y*v.y + v.z*v.z + v.w*v.w;
    #pragma unroll
    for (int o = 1; o < 64; o <<= 1) {
      s  += __shfl_xor(s, o);
      s2 += __shfl_xor(s2, o);
    }
    float m = s * (1.0f / DIM);
    float rb = rsqrtf(s2 * (1.0f / DIM) - m * m + 1e-5f);
    float4 gm = *(const float4*)(g0 + lane * 4);
    float4 bt = *(const float4*)(b0 + lane * 4);
    uint2 st;
    st.x = pack2((v.x - m) * rb * gm.x + bt.x, (v.y - m) * rb * gm.y + bt.y);
    st.y = pack2((v.z - m) * rb * gm.z + bt.z, (v.w - m) * rb * gm.w + bt.w);
    int kc = lane >> 3, quad = (lane >> 1) & 3, jj = 4 * (lane & 1);
    int cid = (row >> 4) * 8 + kc;
    *(uint2*)((ushort*)Hf + (size_t)cid * 512 + (quad * 16 + (row & 15)) * 8 + jj) = st;
  }
}

// ==== fused: K-LN -> Kf (frag order) | Q-LN in place | V swizzle -> Vf ======
// R12: LN branches vectorized to 16B/lane (uint4, G13): 2 rows per wave in
// 32-lane halves (l32 covers d = l32*8..+7); reduce = 5 shfl_xor (o<=16,
// never crosses the half).  Frag indices collapse to ks=l32>>2, quad=l32&3,
// jj=0 -> one contiguous uint4 store per lane (better coalescing).
// LN math identical f32 path + RNE repack -> bit-identical output.
// Grid 7168: j<1024 K-LN (8 rows/blk), j<5120 Q-LN, else V swizzle.
__global__ __launch_bounds__(256) void ln_swz(
    __hip_bfloat16* __restrict__ QKV,
    const float* __restrict__ gamma, const float* __restrict__ beta,
    __hip_bfloat16* __restrict__ Kf, __hip_bfloat16* __restrict__ Vf)
{
  int j = blockIdx.x;
  if (j < 5120) {
    int wave = threadIdx.x >> 6, lane = threadIdx.x & 63;
    int half = lane >> 5, l32 = lane & 31;
    int idx = j * 8 + wave * 2 + half;           // row id: <8192 K, else Q
    size_t base;
    if (idx < 8192) base = (size_t)(idx >> 1) * NQKV + (idx & 1) * DIM;
    else {
      int qi = idx - 8192;
      base = (size_t)(qi >> 3) * NQKV + 2 * NG * DIM + (qi & 7) * DIM;
    }
    __hip_bfloat16* p = QKV + base + l32 * 8;
    uint4 u = *(const uint4*)p;
    float v0 = bflo(u.x), v1 = bfhi(u.x), v2 = bflo(u.y), v3 = bfhi(u.y);
    float v4 = bflo(u.z), v5 = bfhi(u.z), v6 = bflo(u.w), v7 = bfhi(u.w);
    float s  = (v0 + v1) + (v2 + v3) + (v4 + v5) + (v6 + v7);
    float s2 = (v0*v0 + v1*v1) + (v2*v2 + v3*v3) + (v4*v4 + v5*v5) + (v6*v6 + v7*v7);
    #pragma unroll
    for (int o = 1; o < 32; o <<= 1) {
      s  += __shfl_xor(s, o);
      s2 += __shfl_xor(s2, o);
    }
    float m = s * (1.0f / DIM);
    float rb = rsqrtf(s2 * (1.0f / DIM) - m * m + 1e-5f);
    float4 ga = *(const float4*)(gamma + l32 * 8);
    float4 gb = *(const float4*)(gamma + l32 * 8 + 4);
    float4 ba = *(const float4*)(beta + l32 * 8);
    float4 bb = *(const float4*)(beta + l32 * 8 + 4);
    uint4 st;
    st.x = pack2((v0 - m) * rb * ga.x + ba.x, (v1 - m) * rb * ga.y + ba.y);
    st.y = pack2((v2 - m) * rb * ga.z + ba.z, (v3 - m) * rb * ga.w + ba.w);
    st.z = pack2((v4 - m) * rb * gb.x + bb.x, (v5 - m) * rb * gb.y + bb.y);
    st.w = pack2((v6 - m) * rb * gb.z + bb.z, (v7 - m) * rb * gb.w + bb.w);
    if (idx < 8192) {
      int r = idx >> 1, gg = idx & 1;
      int t = r >> 1, b = r & 1;
      int bg = b * NG + gg;
      int kt = t >> 5, tr = t & 31, tc = tr >> 4, col = tr & 15;
      int ks = l32 >> 2, quad = l32 & 3;
      int cid = (bg * 64 + kt) * 16 + tc * 8 + ks;
      *(uint4*)((ushort*)Kf + (size_t)cid * 512 + (quad * 16 + col) * 8) = st;
    } else {
      *(uint4*)p = st;
    }
  } else {
    __shared__ ushort T[64][72];
    int vb = j - 5120;                           // 0..2047
    int t0 = (vb & 31) * 64, d0 = ((vb >> 5) & 3) * 64, bg = vb >> 7;
    int b = bg >> 1, g = bg & 1;
    int tid = threadIdx.x;
    int tr = tid >> 2, c4 = (tid & 3) * 16;
    const ushort* src = (const ushort*)QKV + ((size_t)(t0 + tr) * BSZ + b) * NQKV
                      + NG * DIM + g * DIM + d0 + c4;
    uint4 a0 = *(const uint4*)src;
    uint4 a1 = *(const uint4*)(src + 8);
    *(uint4*)&T[tr][c4]     = a0;
    *(uint4*)&T[tr][c4 + 8] = a1;
    __syncthreads();
    #pragma unroll
    for (int k2 = 0; k2 < 2; ++k2) {
      int u = tid * 2 + k2;                      // (tt,di,quad,col)
      int tt = u >> 8, di = (u >> 6) & 3, qd = (u >> 4) & 3, cl = u & 15;
      ushort tmp[8];
      #pragma unroll
      for (int e = 0; e < 8; ++e) tmp[e] = T[tt * 32 + qd * 8 + e][di * 16 + cl];
      int kt = (t0 >> 5) + tt;
      int dc = (d0 >> 4) + di;
      *(uint4*)((ushort*)Vf + (((size_t)(bg * 64 + kt) * 16 + dc) << 9) + (qd * 16 + cl) * 8)
          = *(uint4*)tmp;
    }
  }
}

// ------ MFMA GEMM: C = A * Wf(frag-order)^T (+bias)(+resid)(relu) -----------
// AFRAG: 1 = A pre-swizzled fragment-order (contiguous 1KB DMA), 0 = row-major.
// OUTMODE: 0 bf16 row-major, 1 f32 row-major, 2 f32 raw partial (split-K),
//          3 bf16 A-frag order (for next GEMM), 4 bf16 raw partial (split-K).
// GM=128 fixed: R10 measured GM=64 as neutral-to-negative -> reverted.
template<int GN, int RELU, int OUTMODE, int AFRAG>
__global__ __launch_bounds__(256) void gemm_mfma(
    const __hip_bfloat16* __restrict__ A,
    const __hip_bfloat16* __restrict__ W,
    const float* __restrict__ bias,
    const float* __restrict__ resid,
    void* __restrict__ outp,
    int M, int N, int K)
{
  constexpr int WCH = GN / 16;
  constexpr int MC  = (GN == 128) ? 4 : 2;
  __shared__ __align__(16) ushort AS[2][4096];
  __shared__ __align__(16) ushort WS[2][WCH * 512];

  const int tid = threadIdx.x;
  const int wave = tid >> 6, lane = tid & 63;
  const int col = lane & 15, quad = lane >> 4;
  const int wm = (GN == 128) ? (wave >> 1) : wave;
  const int wn = (GN == 128) ? (wave & 1) : 0;
  const int bn0 = blockIdx.x * GN;
  const int bm0 = blockIdx.y * 128;
  const bool SPLIT = (OUTMODE == 2 || OUTMODE == 4);
  const int Keff  = SPLIT ? (K / gridDim.z) : K;
  const int kbase = SPLIT ? blockIdx.z * Keff : 0;
  const int kiters = Keff >> 5;

  f32x4 acc[MC][4];
  #pragma unroll
  for (int mc = 0; mc < MC; ++mc)
    #pragma unroll
    for (int nc = 0; nc < 4; ++nc)
      acc[mc][nc] = (f32x4){0.f, 0.f, 0.f, 0.f};

  auto stage = [&](int it, int bufi) {
    int k0 = kbase + it * 32;
    #pragma unroll
    for (int c = 0; c < 2; ++c) {
      int ch = wave * 2 + c;
      if (AFRAG)
        dma16((const ushort*)A + ((((size_t)(bm0 >> 4) + ch) * (K >> 5) + (k0 >> 5)) << 9) + lane * 8,
              &AS[bufi][ch * 512]);
      else
        dma16((const ushort*)A + (size_t)(bm0 + ch * 16 + col) * K + k0 + quad * 8,
              &AS[bufi][ch * 512]);
    }
    #pragma unroll
    for (int c = 0; c < WCH / 4; ++c) {
      int ch = wave * (WCH / 4) + c;
      dma16((const ushort*)W + (((size_t)((bn0 >> 4) + ch) * (K >> 5) + (k0 >> 5)) << 9) + lane * 8,
            &WS[bufi][ch * 512]);
    }
  };

  stage(0, 0);
  for (int it = 0; it < kiters; ++it) {
    int cur = it & 1;
    __syncthreads();
    if (it + 1 < kiters) stage(it + 1, 1 - cur);
    short8 af[MC], bf_[4];
    #pragma unroll
    for (int mc = 0; mc < MC; ++mc)
      af[mc] = *(const short8*)&AS[cur][(wm * MC + mc) * 512 + lane * 8];
    #pragma unroll
    for (int nc = 0; nc < 4; ++nc)
      bf_[nc] = *(const short8*)&WS[cur][(wn * 4 + nc) * 512 + lane * 8];
    #pragma unroll
    for (int mc = 0; mc < MC; ++mc)
      #pragma unroll
      for (int nc = 0; nc < 4; ++nc)
        acc[mc][nc] = __builtin_amdgcn_mfma_f32_16x16x32_bf16(af[mc], bf_[nc], acc[mc][nc], 0, 0, 0);
  }

  #pragma unroll
  for (int nc = 0; nc < 4; ++nc) {
    int n = bn0 + wn * 64 + nc * 16 + col;
    float bv = 0.f;
    if (OUTMODE == 0 || OUTMODE == 1 || OUTMODE == 3) bv = bias[n];
    #pragma unroll
    for (int mc = 0; mc < MC; ++mc) {
      #pragma unroll
      for (int reg = 0; reg < 4; ++reg) {
        int m = bm0 + wm * (MC * 16) + mc * 16 + quad * 4 + reg;
        float v = acc[mc][nc][reg] + bv;
        if ((OUTMODE == 0 || OUTMODE == 1 || OUTMODE == 3) && resid)
          v += resid[(size_t)m * N + n];
        if (RELU) v = fmaxf(v, 0.f);
        if (OUTMODE == 0)
          ((__hip_bfloat16*)outp)[(size_t)m * N + n] = __float2bfloat16(v);
        else if (OUTMODE == 1)
          ((float*)outp)[(size_t)m * N + n] = v;
        else if (OUTMODE == 2)
          ((float*)outp)[(size_t)blockIdx.z * M * N + (size_t)m * N + n] = v;
        else if (OUTMODE == 3) {
          int cid = (m >> 4) * (N >> 5) + (n >> 5);
          int kl = n & 31;
          ((ushort*)outp)[(size_t)cid * 512 + ((kl >> 3) * 16 + (m & 15)) * 8 + (kl & 7)] = bf16bits(v);
        } else {  // 4: bf16 raw partial
          ((ushort*)outp)[(size_t)blockIdx.z * M * N + (size_t)m * N + n] = bf16bits(v);
        }
      }
    }
  }
}

// ---- combine: out = P[0] + P[1] (bf16 partials) + bias + resid (f32) -------
__global__ __launch_bounds__(256) void combine2(
    const ushort* __restrict__ P, const float* __restrict__ bias,
    const float* __restrict__ resid, float* __restrict__ out, int MN)
{
  int i4 = (blockIdx.x * 256 + threadIdx.x) * 4;
  uint2 a = *(const uint2*)(P + i4);
  uint2 b = *(const uint2*)(P + MN + i4);
  float4 r = *(const float4*)(resid + i4);
  float4 bb = *(const float4*)(bias + (i4 & (DIM - 1)));
  float4 o;
  o.x = bflo(a.x) + bflo(b.x) + r.x + bb.x;
  o.y = bfhi(a.x) + bfhi(b.x) + r.y + bb.y;
  o.z = bflo(a.y) + bflo(b.y) + r.z + bb.z;
  o.w = bfhi(a.y) + bfhi(b.y) + r.w + bb.w;
  *(float4*)(out + i4) = o;
}

// ---- combine 4 bf16 split-K partials + bias + resid -> X2 (f32), LN -> H2f -
__global__ __launch_bounds__(256) void combine_ln4(
    const ushort* __restrict__ P, const float* __restrict__ bias,
    const float* __restrict__ resid, float* __restrict__ X2,
    const float* __restrict__ gamma, const float* __restrict__ beta,
    __hip_bfloat16* __restrict__ H2f)
{
  const int MN = ROWS * DIM;
  int wave = threadIdx.x >> 6, lane = threadIdx.x & 63;
  int row = blockIdx.x * 4 + wave;
  size_t i = (size_t)row * DIM + lane * 4;
  uint2 a = *(const uint2*)(P + i);
  uint2 b = *(const uint2*)(P + MN + i);
  uint2 c = *(const uint2*)(P + 2 * (size_t)MN + i);
  uint2 d = *(const uint2*)(P + 3 * (size_t)MN + i);
  float4 r = *(const float4*)(resid + i);
  float4 bb = *(const float4*)(bias + lane * 4);
  float4 v;
  v.x = bflo(a.x) + bflo(b.x) + bflo(c.x) + bflo(d.x) + r.x + bb.x;
  v.y = bfhi(a.x) + bfhi(b.x) + bfhi(c.x) + bfhi(d.x) + r.y + bb.y;
  v.z = bflo(a.y) + bflo(b.y) + bflo(c.y) + bflo(d.y) + r.z + bb.z;
  v.w = bfhi(a.y) + bfhi(b.y) + bfhi(c.y) + bfhi(d.y) + r.w + bb.w;
  *(float4*)(X2 + i) = v;
  float s  = v.x + v.y + v.z + v.w;
  float s2 = v.x*v.x + v.y*v.y + v.z*v.z + v.w*v.w;
  #pragma unroll
  for (int o = 1; o < 64; o <<= 1) {
    s  += __shfl_xor(s, o);
    s2 += __shfl_xor(s2, o);
  }
  float m = s * (1.0f / DIM);
  float rb = rsqrtf(s2 * (1.0f / DIM) - m * m + 1e-5f);
  float4 gm = *(const float4*)(gamma + lane * 4);
  float4 bt = *(const float4*)(beta + lane * 4);
  uint2 st;
  st.x = pack2((v.x - m) * rb * gm.x + bt.x, (v.y - m) * rb * gm.y + bt.y);
  st.y = pack2((v.z - m) * rb * gm.z + bt.z, (v.w - m) * rb * gm.w + bt.w);
  int kc = lane >> 3, quad = (lane >> 1) & 3, jj = 4 * (lane & 1);
  int cid = (row >> 4) * 8 + kc;
  *(uint2*)((ushort*)H2f + (size_t)cid * 512 + (quad * 16 + (row & 15)) * 8 + jj) = st;
}

// ------------- MFMA causal flash attention, 16 heads, D=256 -----------------
// UNCHANGED == R6/R9/R11 (best measured: 235.7-237.3us total, attn 72-74us;
// reproduced three times).  8-wave x 16-rows/wave, swapped QK^T + in-register
// P transpose, K+V double-buffered LDS, 4 waves/SIMD (VGPR 64 + 64 AGPR).
// Balanced 512-block schedule (2/CU), heads {x8, x8+8} co-located per XCD.
// Measured and shelved: Q-LN fusion (spills both reg budgets, R4/R8),
// V-from-L2 (R7), 4x32 waves (R5), GM=64 small-GEMM tiles (R10).
// Partials: z=0 -> Obf (in place), z=1 -> Op1f (m16 in [80,256)),
// z=2 -> dead K/V columns of QKV (freed after ln_swz).
__constant__ int C_NIT[32] = {22,22,22,21,21,20,20,20,20,20,20,19,19,18,18,18,18,17,17,16,16,16,16,16,16,14,14,12,12,12, 8, 4};
__constant__ int C_QB [32] = {10,10,15,15,15, 4, 9, 9,14,14,14,13,13,13, 8, 8,12,12,12, 3, 7, 7,11,11,11, 6, 6, 2, 5, 5, 1, 0};
__constant__ int C_Z  [32] = { 0, 1, 0, 1, 2, 0, 0, 1, 0, 1, 2, 0, 1, 2, 0, 1, 0, 1, 2, 0, 0, 1, 0, 1, 2, 0, 1, 0, 0, 1, 0, 0};
__constant__ int C_K0 [32] = { 0,22, 0,22,43, 0, 0,20, 0,20,40, 0,19,38, 0,18, 0,18,35, 0, 0,16, 0,16,32, 0,14, 0, 0,12, 0, 0};
__constant__ int C_SP [32] = { 1, 1, 1, 1, 1, 0, 1, 1, 1, 1, 1, 1, 1, 1, 1, 1, 1, 1, 1, 0, 1, 1, 1, 1, 1, 1, 1, 0, 1, 1, 0, 0};

__global__ __launch_bounds__(512, 4) void attn_mfma(
    const __hip_bfloat16* QKV,               // Q read here (LN'd by ln_swz)
    const __hip_bfloat16* __restrict__ Kf,   // [bg][64 kt][16 nk][512]
    const __hip_bfloat16* __restrict__ Vf,   // [bg][64 kt][16 dc][512]
    __hip_bfloat16* __restrict__ Obf,        // frag-order [256 m16][64 kc][512]
    __hip_bfloat16* __restrict__ Op1f,       // frag-order z1 partials (m16-80)
    ushort* Op2q,                            // z2 partials in dead QKV K/V cols
    float* __restrict__ Lp)                  // [3][2048][16]
{
  __shared__ __align__(16) ushort KS[2][8192];
  __shared__ __align__(16) ushort VS[2][8192];

  const int tid  = threadIdx.x;
  const int wave = tid >> 6, lane = tid & 63;
  const int col  = lane & 15, quad = lane >> 4;

  const int bid = blockIdx.x;                // 0..511
  const int x8 = bid & 7, j = bid >> 3;      // xcd, local arrival order 0..63
  const int a = j >> 1, odd = j & 1;
  int rank;
  if (a < 16) rank = odd ? (31 - a) : a;
  else        rank = odd ? (a - 16) : (31 - (a - 16));
  const int head = odd * 8 + x8;             // heads {x8, x8+8} per XCD
  const int qb  = C_QB[rank];
  const int z   = C_Z[rank];
  const int nit = C_NIT[rank];
  const int k0  = C_K0[rank];
  const int split = C_SP[rank];

  const int b = head >> 3, hq = head & 7, g = hq >> 2;
  const int bg = b * NG + g;
  const int qw0 = qb * 128 + wave * 16;      // 16 rows per wave, 8 waves

  short8 qf[8];
  {
    int s = qw0 + col;
    const ushort* qp = (const ushort*)QKV + (size_t)s * QROW + b * NQKV
                     + 2 * NG * DIM + hq * DIM + quad * 8;
    #pragma unroll
    for (int ks = 0; ks < 8; ++ks)
      qf[ks] = *(const short8*)(qp + ks * 32);
  }

  short8 onesf;
  #pragma unroll
  for (int i = 0; i < 8; ++i) onesf[i] = (short)0x3F80;

  f32x4 o[16];
  #pragma unroll
  for (int dc = 0; dc < 16; ++dc)
    o[dc] = (f32x4){0.f, 0.f, 0.f, 0.f};
  float l_s[4] = {0.f, 0.f, 0.f, 0.f};

  auto stage = [&](int i, int bufi) {
    int kt = k0 + i;
    const ushort* kb = (const ushort*)Kf + (((size_t)bg * 64 + kt) << 13);
    const ushort* vb = (const ushort*)Vf + (((size_t)bg * 64 + kt) << 13);
    #pragma unroll
    for (int cc = 0; cc < 2; ++cc) {
      int nk = wave * 2 + cc;
      dma16(kb + (nk << 9) + lane * 8, &KS[bufi][nk * 512]);
      dma16(vb + (nk << 9) + lane * 8, &VS[bufi][nk * 512]);
    }
  };

  // shfl source lanes for the in-register P transpose:
  const int sig0 = col + 16 * ((quad & 1) * 2);   // dwords 0,1
  const int sig1 = sig0 + 16;                     // dwords 2,3

  stage(0, 0);
  for (int i = 0; i < nit; ++i) {
    int cur = i & 1;
    __syncthreads();
    if (i + 1 < nit) stage(i + 1, 1 - cur);
    int kt = k0 + i;
    if (kt * 32 > qw0 + 15) continue;

    f32x4 sf[2];
    sf[0] = (f32x4){0.f, 0.f, 0.f, 0.f};
    sf[1] = (f32x4){0.f, 0.f, 0.f, 0.f};
    __builtin_amdgcn_s_setprio(1);
    #pragma unroll
    for (int ks = 0; ks < 8; ++ks) {
      short8 kb0 = *(const short8*)&KS[cur][ks * 512 + lane * 8];
      short8 kb1 = *(const short8*)&KS[cur][(8 + ks) * 512 + lane * 8];
      // swapped: A = K (M = t), B = Q (N = s)
      sf[0] = __builtin_amdgcn_mfma_f32_16x16x32_bf16(kb0, qf[ks], sf[0], 0, 0, 0);
      sf[1] = __builtin_amdgcn_mfma_f32_16x16x32_bf16(kb1, qf[ks], sf[1], 0, 0, 0);
    }
    __builtin_amdgcn_s_setprio(0);

    // C layout (swapped): lane holds s = col, t = quad*4+reg (+tc*16)
    const bool dm = (kt * 32 + 31) > qw0;
    uint32 PK[2][2];                         // [tc][h]: t = tc*16+quad*4+2h+{0,1}
    #pragma unroll
    for (int tc = 0; tc < 2; ++tc) {
      float p[4];
      #pragma unroll
      for (int reg = 0; reg < 4; ++reg) {
        p[reg] = __expf(sf[tc][reg] * 0.0625f);
        if (dm) {
          int tg = kt * 32 + tc * 16 + quad * 4 + reg;
          int sg = qw0 + col;
          if (tg > sg) p[reg] = 0.f;
        }
      }
      PK[tc][0] = pack2(p[0], p[1]);
      PK[tc][1] = pack2(p[2], p[3]);
    }

    // assemble PV A-operand in-register: dword dw = t {quad*8+2dw, +1}
    short8 pa;
    {
      union { uint32 u[4]; short8 s8; } cvt;
      #pragma unroll
      for (int dw = 0; dw < 4; ++dw) {
        int src = (dw < 2) ? sig0 : sig1;
        uint32 a0 = (uint32)__shfl((int)PK[0][dw & 1], src, 64);
        uint32 a1 = (uint32)__shfl((int)PK[1][dw & 1], src, 64);
        cvt.u[dw] = (quad < 2) ? a0 : a1;
      }
      pa = cvt.s8;
    }

    __builtin_amdgcn_s_setprio(1);
    f32x4 zz = (f32x4){0.f, 0.f, 0.f, 0.f};
    f32x4 ps = __builtin_amdgcn_mfma_f32_16x16x32_bf16(pa, onesf, zz, 0, 0, 0);
    #pragma unroll
    for (int r = 0; r < 4; ++r) l_s[r] += ps[r];

    #pragma unroll
    for (int dc = 0; dc < 16; ++dc) {
      short8 vb = *(const short8*)&VS[cur][dc * 512 + lane * 8];
      o[dc] = __builtin_amdgcn_mfma_f32_16x16x32_bf16(pa, vb, o[dc], 0, 0, 0);
    }
    __builtin_amdgcn_s_setprio(0);
  }

  // ---- epilogue: write in A-fragment order ----
  const int colh = col >> 3, coll = col & 7;
  #pragma unroll
  for (int reg = 0; reg < 4; ++reg) {
    int s = qw0 + quad * 4 + reg;
    int m = s * BSZ + b;
    int m16 = m >> 4, ml = m & 15;
    if (!split) {
      float inv = 1.0f / l_s[reg];
      #pragma unroll
      for (int dc = 0; dc < 16; ++dc) {
        int cid = m16 * 64 + hq * 8 + (dc >> 1);
        int qt = (dc & 1) * 2 + colh;
        Obf[(size_t)cid * 512 + (qt * 16 + ml) * 8 + coll] =
            __float2bfloat16(o[dc][reg] * inv);
      }
    } else {
      #pragma unroll
      for (int dc = 0; dc < 16; ++dc) {
        int qt = (dc & 1) * 2 + colh;
        int el = (qt * 16 + ml) * 8 + coll;
        float v = o[dc][reg];
        if (z == 0) {
          Obf[((size_t)(m16 * 64 + hq * 8 + (dc >> 1))) * 512 + el] = __float2bfloat16(v);
        } else if (z == 1) {
          Op1f[((size_t)((m16 - 80) * 64 + hq * 8 + (dc >> 1))) * 512 + el] = __float2bfloat16(v);
        } else {
          size_t o2 = ((size_t)((m16 - 176) * 64 + hq * 8 + (dc >> 1))) * 512 + el;
          Op2q[op2_addr(o2)] = bf16bits(v);
        }
      }
      if (col == 0) Lp[((size_t)z * 2048 + s) * 16 + head] = l_s[reg];
    }
  }
}

// ---- merge split partials (frag space, coalesced): 2- or 3-way -------------
// rows m16 in [80,256): Obf += Op1f (+ Op2 for m16>=176), / (l0+l1(+l2)).
__global__ __launch_bounds__(256) void attn_norm(
    __hip_bfloat16* __restrict__ Obf, const __hip_bfloat16* __restrict__ Op1f,
    const ushort* __restrict__ Op2q, const float* __restrict__ Lp)
{
  int i8 = blockIdx.x * 256 + threadIdx.x;   // over 176*64*64 = 720896
  int cidr = i8 >> 6;                        // (m16r*64 + kc)
  int lane = i8 & 63;
  int m16r = cidr >> 6, kc = cidr & 63;
  int m16 = m16r + 80;
  int m = m16 * 16 + (lane & 15);
  int k = kc * 32 + (lane >> 4) * 8;
  int s = m >> 1, b = m & 1, hq = k >> 8;
  int head = b * 8 + hq;
  float l = Lp[(size_t)s * 16 + head] + Lp[(size_t)(2048 + s) * 16 + head];
  ushort* a = (ushort*)Obf + (((size_t)m16 * 64 + kc) << 9) + lane * 8;
  const ushort* c = (const ushort*)Op1f + (((size_t)m16r * 64 + kc) << 9) + lane * 8;
  uint4 ua = *(const uint4*)a;
  uint4 uc = *(const uint4*)c;
  float v0 = bflo(ua.x) + bflo(uc.x), v1 = bfhi(ua.x) + bfhi(uc.x);
  float v2 = bflo(ua.y) + bflo(uc.y), v3 = bfhi(ua.y) + bfhi(uc.y);
  float v4 = bflo(ua.z) + bflo(uc.z), v5 = bfhi(ua.z) + bfhi(uc.z);
  float v6 = bflo(ua.w) + bflo(uc.w), v7 = bfhi(ua.w) + bfhi(uc.w);
  if (s >= 1408) {                           // qb >= 11: 3-way (block-uniform)
    l += Lp[(size_t)(4096 + s) * 16 + head];
    size_t o2 = (((size_t)(m16 - 176) * 64 + kc) << 9) + lane * 8;
    uint4 ue = *(const uint4*)(Op2q + op2_addr(o2));
    v0 += bflo(ue.x); v1 += bfhi(ue.x);
    v2 += bflo(ue.y); v3 += bfhi(ue.y);
    v4 += bflo(ue.z); v5 += bfhi(ue.z);
    v6 += bflo(ue.w); v7 += bfhi(ue.w);
  }
  float inv = 1.0f / l;
  uint4 st;
  st.x = pack2(v0 * inv, v1 * inv);
  st.y = pack2(v2 * inv, v3 * inv);
  st.z = pack2(v4 * inv, v5 * inv);
  st.w = pack2(v6 * inv, v7 * inv);
  *(uint4*)a = st;
}

// ---------------------------------------------------------------------------
extern "C" void kernel_launch(void* const* d_in, const int* in_sizes, int n_in,
                              void* d_out, int out_size, void* d_ws, size_t ws_size,
                              hipStream_t stream)
{
  const float* x   = (const float*)d_in[0];
  const float* g0  = (const float*)d_in[1];
  const float* b0  = (const float*)d_in[2];
  const float* g1  = (const float*)d_in[3];
  const float* b1  = (const float*)d_in[4];
  const float* gn  = (const float*)d_in[5];
  const float* bn  = (const float*)d_in[6];
  const float* wk  = (const float*)d_in[7];
  const float* bk  = (const float*)d_in[8];
  const float* wv  = (const float*)d_in[9];
  const float* bv  = (const float*)d_in[10];
  const float* wq  = (const float*)d_in[11];
  const float* bq  = (const float*)d_in[12];
  const float* wo  = (const float*)d_in[13];
  const float* bo  = (const float*)d_in[14];
  const float* w1  = (const float*)d_in[15];
  const float* bf1 = (const float*)d_in[16];
  const float* w2  = (const float*)d_in[17];
  const float* bf2 = (const float*)d_in[18];

  char* ws = (char*)d_ws;
  const size_t MB = 1024 * 1024;
  __hip_bfloat16* QKV = (__hip_bfloat16*)(ws);            // 24MB [K/V cols dead after ln_swz -> hold z2 partials]
  __hip_bfloat16* Pwo = (__hip_bfloat16*)(ws);            //  8MB bf16 partials [after attn]
  __hip_bfloat16* Pw2 = (__hip_bfloat16*)(ws + 8  * MB);  //  4MB bf16 partials [after attn]
  float*          X2  = (float*)         (ws + 16 * MB);  //  4MB [after attn]
  __hip_bfloat16* H2f = (__hip_bfloat16*)(ws + 20 * MB);  //  2MB [after attn]
  __hip_bfloat16* F1f = (__hip_bfloat16*)(ws + 22 * MB);  //  4MB [after attn]
  __hip_bfloat16* Hf  = (__hip_bfloat16*)(ws + 24 * MB);  //  2MB [dead after QKV gemm]
  __hip_bfloat16* Kf  = (__hip_bfloat16*)(ws + 24 * MB);  //  4MB [written after Hf dead]
  __hip_bfloat16* Vf  = (__hip_bfloat16*)(ws + 28 * MB);  //  4MB
  __hip_bfloat16* Obf = (__hip_bfloat16*)(ws + 32 * MB);  // 16MB frag-order O
  __hip_bfloat16* Op1f= (__hip_bfloat16*)(ws + 48 * MB);  // 11MB z1 partials (m16 in [80,256))
  float*          BC  = (float*)         (ws + 59 * MB);  // 12KB
  float*          Lp  = (float*)         (ws + 59 * MB + 64 * 1024);  // 384KB [3][2048][16]
  __hip_bfloat16* WB  = (__hip_bfloat16*)(ws + 61 * MB);  //  3MB weights (frag order)

  __hip_bfloat16* woB = WB + 786432;
  __hip_bfloat16* w1B = WB + 1310720;
  __hip_bfloat16* w2B = WB + 1441792;

  // 0+1. weights -> frag-order bf16 + bias concat | LN(x) -> Hf (fused)
  misc0<<<1795, 256, 0, stream>>>(wk, wv, wq, wo, w1, w2, bk, bv, bq, WB, BC, x, g0, b0, Hf);
  // 2. fused K|V|Q projection (one GEMM, N=3072, frag-order A and W)
  gemm_mfma<128,0,0,1><<<dim3(NQKV/128, ROWS/128), 256, 0, stream>>>(Hf, WB, BC, nullptr, QKV, ROWS, NQKV, DIM);
  // 3. K-LN -> Kf | Q-LN in place | V swizzle -> Vf (uint4-vectorized LN)
  ln_swz<<<7168, 256, 0, stream>>>(QKV, gn, bn, Kf, Vf);
  // 4. attention (8-wave/16-row decomposition, 4 waves/SIMD) + merge
  attn_mfma<<<512, 512, 0, stream>>>(QKV, Kf, Vf, Obf, Op1f, (ushort*)QKV, Lp);
  attn_norm<<<2816, 256, 0, stream>>>(Obf, Op1f, (const ushort*)QKV, Lp);
  // 5. x2 = x + Obf @ wo^T + bo  (AFRAG staging, bf16 split-K=4 partials)
  gemm_mfma<64,0,4,1><<<dim3(DIM/64, ROWS/128, 4), 256, 0, stream>>>(Obf, woB, nullptr, nullptr, Pwo, ROWS, DIM, NQH*DIM);
  combine_ln4<<<ROWS / 4, 256, 0, stream>>>((const ushort*)Pwo, bo, x, X2, g1, b1, H2f);
  // 6. FFN (w1: frag-order out; w2: AFRAG staging, bf16 split-K=2 partials)
  gemm_mfma<64,1,3,1><<<dim3((2*DIM)/64, ROWS/128), 256, 0, stream>>>(H2f, w1B, bf1, nullptr, F1f, ROWS, 2*DIM, DIM);
  gemm_mfma<64,0,4,1><<<dim3(DIM/64, ROWS/128, 2), 256, 0, stream>>>(F1f, w2B, nullptr, nullptr, Pw2, ROWS, DIM, 2*DIM);
  combine2<<<ROWS*DIM/1024, 256, 0, stream>>>((const ushort*)Pw2, bf2, X2, (float*)d_out, ROWS*DIM);
}